// Round 5
// baseline (15771.049 us; speedup 1.0000x reference)
//
#include <hip/hip_runtime.h>
#include <cmath>

namespace {

constexpr int BATCH = 64;
constexpr int NREG  = 49;
constexpr int FEATN = 2048;
constexpr int FHN   = 512;
constexpr int HID   = 512;
constexpr int EMBN  = 512;
constexpr int VOC   = 32000;
constexpr int TSTEPS= 40;
constexpr int G4    = 2048;       // 4*H
constexpr int NVT   = VOC / 128;  // 250 v-tiles for logits
constexpr int NBLK  = 256;        // persistent grid (1 block/CU)

typedef short bf16x8 __attribute__((ext_vector_type(8)));
typedef float f32x4  __attribute__((ext_vector_type(4)));

__device__ __forceinline__ float sigm(float x) { return 1.0f / (1.0f + expf(-x)); }

__device__ __forceinline__ unsigned short f2bf(float f) {
  unsigned u = __float_as_uint(f);
  unsigned r = (u + 0x7fffu + ((u >> 16) & 1u)) >> 16;   // RNE
  return (unsigned short)r;
}
__device__ __forceinline__ float bf2f(unsigned short h) {
  return __uint_as_float(((unsigned)h) << 16);
}

__device__ __forceinline__ bool better(float a, int ia, float b, int ib) {
  return a > b || (a == b && ia < ib);
}
__device__ __forceinline__ void top2_merge(float& v1, int& i1, float& v2, int& i2,
                                           float u1, int j1, float u2, int j2) {
  if (better(u1, j1, v1, i1)) {
    float t = v1; int ti = i1;
    v1 = u1; i1 = j1;
    if (better(u2, j2, t, ti)) { v2 = u2; i2 = j2; } else { v2 = t; i2 = ti; }
  } else {
    if (better(u1, j1, v2, i2)) { v2 = u1; i2 = j1; }
  }
}
__device__ __forceinline__ void lse_merge(float& m, float& s, float om, float os) {
  float nm = fmaxf(m, om);
  float ns = 0.f;
  if (m  > -INFINITY) ns += s  * expf(m  - nm);
  if (om > -INFINITY) ns += os * expf(om - nm);
  m = nm; s = ns;
}

// ================= shared-memory union =================
struct SmemC {                       // phase C (logits)
  unsigned short hl[32768];          // 64KB h1 tile, XOR-swizzled
  float rm[512], rs[512], rv1[512], rv2[512];
  int   ri1[512], ri2[512];
};
struct SmemAB {                      // phases A/B (lstm): [gate][batch][j_local]
  float gs[4][64][64];               // 64KB
};
struct SmemD {                       // phase D (sample)
  float rm[256], rs[256], rv1[256], rv2[256];
  int   ri1[256], ri2[256];
  float s1[512], s2[512];
};
union Smem { SmemC c; SmemAB ab; SmemD d; };

// ================= barriers =================
// bar layout (uints): shard counters at 32*s (s=0..7), master at 288, gen at 320,
//                     mini counter at 352, mini gen at 384
__device__ __forceinline__ void fullbar(unsigned* bar) {
  __syncthreads();
  if (threadIdx.x == 0) {
    __threadfence();
    unsigned gen = __hip_atomic_load(bar + 320, __ATOMIC_RELAXED, __HIP_MEMORY_SCOPE_AGENT);
    const int shard = blockIdx.x & 7;
    unsigned a = __hip_atomic_fetch_add(bar + shard * 32, 1u, __ATOMIC_ACQ_REL, __HIP_MEMORY_SCOPE_AGENT);
    if (a == 31u) {
      __hip_atomic_store(bar + shard * 32, 0u, __ATOMIC_RELAXED, __HIP_MEMORY_SCOPE_AGENT);
      unsigned m = __hip_atomic_fetch_add(bar + 288, 1u, __ATOMIC_ACQ_REL, __HIP_MEMORY_SCOPE_AGENT);
      if (m == 7u) {
        __hip_atomic_store(bar + 288, 0u, __ATOMIC_RELAXED, __HIP_MEMORY_SCOPE_AGENT);
        __hip_atomic_fetch_add(bar + 320, 1u, __ATOMIC_RELEASE, __HIP_MEMORY_SCOPE_AGENT);
      }
    }
    while (__hip_atomic_load(bar + 320, __ATOMIC_RELAXED, __HIP_MEMORY_SCOPE_AGENT) == gen)
      __builtin_amdgcn_s_sleep(2);
    __threadfence();
  }
  __syncthreads();
}

__device__ __forceinline__ void minibar(unsigned* bar) {   // blocks 0..7 only
  __syncthreads();
  if (threadIdx.x == 0) {
    __threadfence();
    unsigned gen = __hip_atomic_load(bar + 384, __ATOMIC_RELAXED, __HIP_MEMORY_SCOPE_AGENT);
    unsigned a = __hip_atomic_fetch_add(bar + 352, 1u, __ATOMIC_ACQ_REL, __HIP_MEMORY_SCOPE_AGENT);
    if (a == 7u) {
      __hip_atomic_store(bar + 352, 0u, __ATOMIC_RELAXED, __HIP_MEMORY_SCOPE_AGENT);
      __hip_atomic_fetch_add(bar + 384, 1u, __ATOMIC_RELEASE, __HIP_MEMORY_SCOPE_AGENT);
    }
    while (__hip_atomic_load(bar + 384, __ATOMIC_RELAXED, __HIP_MEMORY_SCOPE_AGENT) == gen)
      __builtin_amdgcn_s_sleep(1);
    __threadfence();
  }
  __syncthreads();
}

// ================= prep kernels (one-time, unchanged from r3/r4) =================

__global__ __launch_bounds__(256) void k_trans(const float* __restrict__ src,
    unsigned short* __restrict__ dhi, unsigned short* __restrict__ dlo, int K, int N) {
  __shared__ float tile[32][33];
  const int k0 = blockIdx.x * 32, n0 = blockIdx.y * 32;
  const int tx = threadIdx.x & 31, ty = threadIdx.x >> 5;
#pragma unroll
  for (int r = ty; r < 32; r += 8) tile[r][tx] = src[(size_t)(k0 + r) * N + n0 + tx];
  __syncthreads();
#pragma unroll
  for (int r = ty; r < 32; r += 8) {
    float v = tile[tx][r];
    unsigned short hv = f2bf(v);
    size_t o = (size_t)(n0 + r) * K + k0 + tx;
    dhi[o] = hv;
    dlo[o] = f2bf(v - bf2f(hv));
  }
}

__global__ void k_split(const float* __restrict__ src, unsigned short* __restrict__ dhi,
                        unsigned short* __restrict__ dlo) {
  const size_t i = (size_t)blockIdx.x * 256 + threadIdx.x;
  const float4* p = reinterpret_cast<const float4*>(src) + i * 2;
  float4 a = p[0], b = p[1];
  float v[8] = {a.x, a.y, a.z, a.w, b.x, b.y, b.z, b.w};
  unsigned short hi[8], lo[8];
#pragma unroll
  for (int j = 0; j < 8; ++j) {
    hi[j] = f2bf(v[j]);
    lo[j] = f2bf(v[j] - bf2f(hi[j]));
  }
  uint4 oh, ol;
  oh.x = hi[0] | (hi[1] << 16); oh.y = hi[2] | (hi[3] << 16);
  oh.z = hi[4] | (hi[5] << 16); oh.w = hi[6] | (hi[7] << 16);
  ol.x = lo[0] | (lo[1] << 16); ol.y = lo[2] | (lo[3] << 16);
  ol.z = lo[4] | (lo[5] << 16); ol.w = lo[6] | (lo[7] << 16);
  reinterpret_cast<uint4*>(dhi)[i] = oh;
  reinterpret_cast<uint4*>(dlo)[i] = ol;
}

__global__ void k_emb2bf(const float* __restrict__ emb, unsigned short* __restrict__ ebf) {
  const size_t i = (size_t)blockIdx.x * 256 + threadIdx.x;
  const float4* p = reinterpret_cast<const float4*>(emb) + i * 2;
  float4 a = p[0], b = p[1];
  uint4 o;
  o.x = (unsigned)f2bf(a.x) | ((unsigned)f2bf(a.y) << 16);
  o.y = (unsigned)f2bf(a.z) | ((unsigned)f2bf(a.w) << 16);
  o.z = (unsigned)f2bf(b.x) | ((unsigned)f2bf(b.y) << 16);
  o.w = (unsigned)f2bf(b.z) | ((unsigned)f2bf(b.w) << 16);
  reinterpret_cast<uint4*>(ebf)[i] = o;
}

__global__ __launch_bounds__(256) void k_feat_mfma(
    const unsigned short* __restrict__ Ahi, const unsigned short* __restrict__ Alo,
    const unsigned short* __restrict__ Bhi, const unsigned short* __restrict__ Blo,
    const float* __restrict__ bias, float* __restrict__ femb) {
  const int m0 = blockIdx.x * 64, n0 = blockIdx.y * 64;
  const int tid = threadIdx.x, lane = tid & 63, w = tid >> 6;
  const int l15 = lane & 15, l4 = lane >> 4;
  f32x4 acc[4];
#pragma unroll
  for (int nt = 0; nt < 4; ++nt) acc[nt] = (f32x4){0.f, 0.f, 0.f, 0.f};
  const size_t arow = (size_t)(m0 + w * 16 + l15) * FEATN;
  for (int kk = 0; kk < FEATN / 32; ++kk) {
    const int k = kk * 32 + l4 * 8;
    bf16x8 a1 = *reinterpret_cast<const bf16x8*>(Ahi + arow + k);
    bf16x8 a2 = *reinterpret_cast<const bf16x8*>(Alo + arow + k);
#pragma unroll
    for (int nt = 0; nt < 4; ++nt) {
      const size_t brow = (size_t)(n0 + nt * 16 + l15) * FEATN + k;
      bf16x8 b1 = *reinterpret_cast<const bf16x8*>(Bhi + brow);
      bf16x8 b2 = *reinterpret_cast<const bf16x8*>(Blo + brow);
      acc[nt] = __builtin_amdgcn_mfma_f32_16x16x32_bf16(a1, b1, acc[nt], 0, 0, 0);
      acc[nt] = __builtin_amdgcn_mfma_f32_16x16x32_bf16(a1, b2, acc[nt], 0, 0, 0);
      acc[nt] = __builtin_amdgcn_mfma_f32_16x16x32_bf16(a2, b1, acc[nt], 0, 0, 0);
    }
  }
#pragma unroll
  for (int nt = 0; nt < 4; ++nt)
#pragma unroll
    for (int i = 0; i < 4; ++i) {
      int m = m0 + w * 16 + l4 * 4 + i, n = n0 + nt * 16 + l15;
      femb[(size_t)m * FHN + n] = tanhf(acc[nt][i] + bias[n]);
    }
}

__global__ void k_mean(const float* __restrict__ femb, float* __restrict__ fmean) {
  const int gid = blockIdx.x * 256 + threadIdx.x;  // 32768
  const int b = gid >> 9, f = gid & 511;
  float s = 0.f;
  for (int n = 0; n < NREG; ++n) s += femb[(size_t)(b * NREG + n) * FHN + f];
  fmean[gid] = s * (1.0f / NREG);
}

__global__ __launch_bounds__(256) void k_h0c0(const float* __restrict__ fmean,
    const float* __restrict__ Wc, const float* __restrict__ bc,
    const float* __restrict__ Wh, const float* __restrict__ bh,
    float* __restrict__ hbuf, float* __restrict__ cbuf,
    unsigned short* __restrict__ hshi, unsigned short* __restrict__ hslo) {
  const int n0 = blockIdx.x * 64, l = blockIdx.y, isH = blockIdx.z;
  const float* W   = (isH ? Wh : Wc) + (size_t)l * FHN * HID;
  const float* bias= (isH ? bh : bc) + l * HID;
  float* outp      = (isH ? hbuf : cbuf) + (size_t)l * BATCH * HID;
  __shared__ float As[16][68], Bs[16][68];
  const int tid = threadIdx.x, tx = tid & 15, ty = tid >> 4;
  float acc[4][4] = {};
  for (int k0 = 0; k0 < FHN; k0 += 16) {
#pragma unroll
    for (int e = 0; e < 4; ++e) { int idx = tid + e * 256, m = idx >> 4, k = idx & 15; As[k][m] = fmean[m * FHN + k0 + k]; }
#pragma unroll
    for (int e = 0; e < 4; ++e) { int idx = tid + e * 256, k = idx >> 6, n = idx & 63; Bs[k][n] = W[(size_t)(k0 + k) * HID + n0 + n]; }
    __syncthreads();
#pragma unroll
    for (int k = 0; k < 16; ++k) {
      float4 av = *(const float4*)&As[k][ty * 4];
      float4 bv = *(const float4*)&Bs[k][tx * 4];
      float a[4] = {av.x, av.y, av.z, av.w}, b[4] = {bv.x, bv.y, bv.z, bv.w};
#pragma unroll
      for (int i = 0; i < 4; ++i)
#pragma unroll
        for (int j = 0; j < 4; ++j) acc[i][j] = fmaf(a[i], b[j], acc[i][j]);
    }
    __syncthreads();
  }
#pragma unroll
  for (int i = 0; i < 4; ++i) {
    int m = ty * 4 + i, n = n0 + tx * 4;
    float vals[4];
#pragma unroll
    for (int j = 0; j < 4; ++j) vals[j] = acc[i][j] + bias[n + j];
    *(float4*)&outp[(size_t)m * HID + n] = make_float4(vals[0], vals[1], vals[2], vals[3]);
    if (isH) {
#pragma unroll
      for (int j = 0; j < 4; ++j) {
        unsigned short hv = f2bf(vals[j]);
        size_t o = (size_t)l * BATCH * HID + (size_t)m * HID + n + j;  // parity-0 slot
        hshi[o] = hv;
        hslo[o] = f2bf(vals[j] - bf2f(hv));
      }
    }
  }
}

__global__ void k_initx(unsigned short* __restrict__ xhi, unsigned short* __restrict__ xlo) {
  const int i = blockIdx.x * 256 + threadIdx.x;
  xhi[i] = 0x4040; xlo[i] = 0;      // 3.0 exact in bf16
}

__global__ void k_zero(unsigned* __restrict__ bar) {
  bar[threadIdx.x] = 0;             // 512 uints
}

// ================= persistent-kernel phase bodies =================

// ---- LSTM layer: 8 blocks x 16 waves; wave w -> gate w>>2, chunk w&3 ----
__device__ __forceinline__ void lstm_block(int l, int blk, int tid,
    const unsigned short* __restrict__ xh, const unsigned short* __restrict__ xl,
    const unsigned short* __restrict__ hh, const unsigned short* __restrict__ hlo_,
    const unsigned short* __restrict__ wg, const float* __restrict__ bl,
    float* __restrict__ hbuf, float* __restrict__ cbuf,
    unsigned short* __restrict__ ho_hi, unsigned short* __restrict__ ho_lo,
    Smem& sm) {
  const int lane = tid & 63, w = tid >> 6;
  const int l15 = lane & 15, l4 = lane >> 4;
  const int g = w >> 2, chunk = w & 3;
  const int ncol = g * 512 + blk * 64 + chunk * 16;
  const size_t WGM = (size_t)G4 * 512;
  const unsigned short* wih_hi = wg + (((size_t)l * 2 + 0) * 2 + 0) * WGM;
  const unsigned short* wih_lo = wih_hi + WGM;
  const unsigned short* whh_hi = wg + (((size_t)l * 2 + 1) * 2 + 0) * WGM;
  const unsigned short* whh_lo = whh_hi + WGM;
  const size_t nrow = (size_t)(ncol + l15) * 512;
  f32x4 acc[4];
#pragma unroll
  for (int mt = 0; mt < 4; ++mt) acc[mt] = (f32x4){0.f, 0.f, 0.f, 0.f};
#pragma unroll
  for (int kk = 0; kk < 16; ++kk) {          // x @ Wih
    const int k = kk * 32 + l4 * 8;
    bf16x8 b1 = *reinterpret_cast<const bf16x8*>(wih_hi + nrow + k);
    bf16x8 b2 = *reinterpret_cast<const bf16x8*>(wih_lo + nrow + k);
#pragma unroll
    for (int mt = 0; mt < 4; ++mt) {
      const size_t ar = (size_t)(mt * 16 + l15) * 512 + k;
      bf16x8 a1 = *reinterpret_cast<const bf16x8*>(xh + ar);
      bf16x8 a2 = *reinterpret_cast<const bf16x8*>(xl + ar);
      acc[mt] = __builtin_amdgcn_mfma_f32_16x16x32_bf16(a1, b1, acc[mt], 0, 0, 0);
      acc[mt] = __builtin_amdgcn_mfma_f32_16x16x32_bf16(a1, b2, acc[mt], 0, 0, 0);
      acc[mt] = __builtin_amdgcn_mfma_f32_16x16x32_bf16(a2, b1, acc[mt], 0, 0, 0);
    }
  }
#pragma unroll
  for (int kk = 0; kk < 16; ++kk) {          // h @ Whh
    const int k = kk * 32 + l4 * 8;
    bf16x8 b1 = *reinterpret_cast<const bf16x8*>(whh_hi + nrow + k);
    bf16x8 b2 = *reinterpret_cast<const bf16x8*>(whh_lo + nrow + k);
#pragma unroll
    for (int mt = 0; mt < 4; ++mt) {
      const size_t ar = (size_t)(mt * 16 + l15) * 512 + k;
      bf16x8 a1 = *reinterpret_cast<const bf16x8*>(hh + ar);
      bf16x8 a2 = *reinterpret_cast<const bf16x8*>(hlo_ + ar);
      acc[mt] = __builtin_amdgcn_mfma_f32_16x16x32_bf16(a1, b1, acc[mt], 0, 0, 0);
      acc[mt] = __builtin_amdgcn_mfma_f32_16x16x32_bf16(a1, b2, acc[mt], 0, 0, 0);
      acc[mt] = __builtin_amdgcn_mfma_f32_16x16x32_bf16(a2, b1, acc[mt], 0, 0, 0);
    }
  }
#pragma unroll
  for (int mt = 0; mt < 4; ++mt)
#pragma unroll
    for (int i = 0; i < 4; ++i)
      sm.ab.gs[g][mt * 16 + l4 * 4 + i][chunk * 16 + l15] = acc[mt][i];
  __syncthreads();
#pragma unroll
  for (int e = 0; e < 4; ++e) {
    const int idx = tid * 4 + e;             // 4096 cells / 1024 threads
    const int b = idx >> 6, jl = idx & 63, j = blk * 64 + jl;
    float gi = sm.ab.gs[0][b][jl] + bl[l * 2048 + j];
    float gf = sm.ab.gs[1][b][jl] + bl[l * 2048 + 512 + j];
    float gg = sm.ab.gs[2][b][jl] + bl[l * 2048 + 1024 + j];
    float go = sm.ab.gs[3][b][jl] + bl[l * 2048 + 1536 + j];
    const size_t o = (size_t)l * BATCH * HID + (size_t)b * HID + j;
    float cn = sigm(gf) * cbuf[o] + sigm(gi) * tanhf(gg);
    float hn = sigm(go) * tanhf(cn);
    cbuf[o] = cn; hbuf[o] = hn;
    unsigned short hv = f2bf(hn);
    const size_t oh = (size_t)b * HID + j;
    ho_hi[oh] = hv; ho_lo[oh] = f2bf(hn - bf2f(hv));
  }
  __syncthreads();
}

// ---- per-block prefetch of own phase-C working set into local L2 ----
__device__ __forceinline__ void prefetch_tile(int blk, int tid,
    const unsigned short* __restrict__ embbf, const float* __restrict__ gum_t) {
  unsigned acc = 0;
  const uint4* ep = reinterpret_cast<const uint4*>(embbf + (size_t)blk * 128 * 512);
#pragma unroll
  for (int i = 0; i < 8; ++i) {      // 8192 uint4 = 128KB
    uint4 v = ep[tid + i * 1024];
    acc += v.x + v.y + v.z + v.w;
  }
  const int bb = tid >> 5, ii = tid & 31;
#pragma unroll
  for (int j = 0; j < 2; ++j) {      // gumbel slice: 64 b x 32 uint4
    const uint4* gp = reinterpret_cast<const uint4*>(gum_t + (size_t)(bb + j * 32) * VOC + blk * 128);
    uint4 v = gp[ii];
    acc += v.x + v.y + v.z + v.w;
  }
  asm volatile("" :: "v"(acc));
}

// ---- logits tile: 250 blocks x 16 waves; wave w -> vsub w>>1, bhalf w&1 ----
__device__ __forceinline__ void logits_block(int blk, int tid,
    const unsigned short* __restrict__ embbf, const unsigned short* __restrict__ h1hi,
    const float* __restrict__ gum_t, float* __restrict__ red, Smem& sm) {
  const int v0 = blk * 128;
  const int lane = tid & 63, w = tid >> 6;
  const int l15 = lane & 15, l4 = lane >> 4;
  const int vsub = w >> 1, bhalf = w & 1;
#pragma unroll
  for (int i = 0; i < 4; ++i) {      // stage h1(hi) -> LDS, XOR swizzle
    int c = tid + i * 1024;
    int row = c >> 6;
    int inb = (c & 63) << 4;
    uint4 v = *reinterpret_cast<const uint4*>(h1hi + ((size_t)c << 3));
    int sw = inb ^ ((row & 7) << 4);
    *reinterpret_cast<uint4*>(reinterpret_cast<char*>(sm.c.hl) + row * 1024 + sw) = v;
  }
  __syncthreads();

  f32x4 acc[2];
  acc[0] = (f32x4){0.f, 0.f, 0.f, 0.f};
  acc[1] = (f32x4){0.f, 0.f, 0.f, 0.f};
  const unsigned short* aptr = embbf + (size_t)(v0 + vsub * 16 + l15) * 512 + l4 * 8;
#pragma unroll
  for (int ks = 0; ks < 16; ++ks) {
    bf16x8 a0 = *reinterpret_cast<const bf16x8*>(aptr + ks * 32);
#pragma unroll
    for (int nl = 0; nl < 2; ++nl) {
      int row = (bhalf * 2 + nl) * 16 + l15;
      int inb = ks * 64 + l4 * 16;
      int sw = inb ^ ((row & 7) << 4);
      bf16x8 bb = *reinterpret_cast<const bf16x8*>(reinterpret_cast<const char*>(sm.c.hl) + row * 1024 + sw);
      acc[nl] = __builtin_amdgcn_mfma_f32_16x16x32_bf16(a0, bb, acc[nl], 0, 0, 0);
    }
  }

  const int vb = v0 + vsub * 16 + l4 * 4;
#pragma unroll
  for (int nl = 0; nl < 2; ++nl) {
    const int b = (bhalf * 2 + nl) * 16 + l15;
    float4 g0 = *reinterpret_cast<const float4*>(gum_t + (size_t)b * VOC + vb);
    float lg[4] = {acc[nl][0], acc[nl][1], acc[nl][2], acc[nl][3]};
    float gv[4] = {g0.x, g0.y, g0.z, g0.w};
    float mx = fmaxf(fmaxf(lg[0], lg[1]), fmaxf(lg[2], lg[3]));
    float ss = 0.f;
    float v1 = -INFINITY, v2 = -INFINITY; int i1 = 0x7fffffff, i2 = 0x7fffffff;
#pragma unroll
    for (int i = 0; i < 4; ++i) {
      ss += expf(lg[i] - mx);
      float val = lg[i] + gv[i];
      int idx = vb + i;
      if (better(val, idx, v1, i1)) { v2 = v1; i2 = i1; v1 = val; i1 = idx; }
      else if (better(val, idx, v2, i2)) { v2 = val; i2 = idx; }
    }
#pragma unroll
    for (int mask = 16; mask <= 32; mask <<= 1) {
      float om = __shfl_xor(mx, mask);
      float os = __shfl_xor(ss, mask);
      float u1 = __shfl_xor(v1, mask); int j1 = __shfl_xor(i1, mask);
      float u2 = __shfl_xor(v2, mask); int j2 = __shfl_xor(i2, mask);
      lse_merge(mx, ss, om, os);
      top2_merge(v1, i1, v2, i2, u1, j1, u2, j2);
    }
    if (lane < 16) {
      int slot = (w * 2 + nl) * 16 + l15;
      sm.c.rm[slot] = mx; sm.c.rs[slot] = ss;
      sm.c.rv1[slot] = v1; sm.c.ri1[slot] = i1; sm.c.rv2[slot] = v2; sm.c.ri2[slot] = i2;
    }
  }
  __syncthreads();
  if (tid < 64) {
    const int b = tid, bh = b >> 5, nl = (b >> 4) & 1, c = b & 15;
    int s0 = ((bh) * 2 + nl) * 16 + c;           // vsub = 0
    float M = sm.c.rm[s0], S = sm.c.rs[s0], V1 = sm.c.rv1[s0], V2 = sm.c.rv2[s0];
    int I1 = sm.c.ri1[s0], I2 = sm.c.ri2[s0];
#pragma unroll
    for (int vs = 1; vs < 8; ++vs) {
      int sl = ((vs * 2 + bh) * 2 + nl) * 16 + c;
      lse_merge(M, S, sm.c.rm[sl], sm.c.rs[sl]);
      top2_merge(V1, I1, V2, I2, sm.c.rv1[sl], sm.c.ri1[sl], sm.c.rv2[sl], sm.c.ri2[sl]);
    }
    float* rp = red + ((size_t)blk * 64 + tid) * 8;
    rp[0] = M; rp[1] = S;
    rp[2] = V1; rp[3] = __int_as_float(I1);
    rp[4] = V2; rp[5] = __int_as_float(I2);
  }
}

// ---- final reduce + exact f32 rescore + sample (blocks 0..63, 1024 threads) ----
__device__ __forceinline__ void sample_block(int b, int tid, int t,
    const float* __restrict__ red, const float* __restrict__ emb,
    const float* __restrict__ h1f, const float* __restrict__ gum_t,
    unsigned short* __restrict__ xhi, unsigned short* __restrict__ xlo,
    float* __restrict__ out, Smem& sm) {
  if (tid < 256) {
    float m = -INFINITY, s = 0.f, v1 = -INFINITY, v2 = -INFINITY;
    int i1 = 0x7fffffff, i2 = 0x7fffffff;
    if (tid < NVT) {
      const float* rp = red + ((size_t)tid * 64 + b) * 8;
      m = rp[0]; s = rp[1];
      v1 = rp[2]; i1 = __float_as_int(rp[3]);
      v2 = rp[4]; i2 = __float_as_int(rp[5]);
    }
    sm.d.rm[tid] = m; sm.d.rs[tid] = s;
    sm.d.rv1[tid] = v1; sm.d.ri1[tid] = i1; sm.d.rv2[tid] = v2; sm.d.ri2[tid] = i2;
  }
  __syncthreads();
  for (int off = 128; off > 0; off >>= 1) {
    if (tid < off) {
      float M = sm.d.rm[tid], S = sm.d.rs[tid];
      lse_merge(M, S, sm.d.rm[tid + off], sm.d.rs[tid + off]);
      sm.d.rm[tid] = M; sm.d.rs[tid] = S;
      float a1 = sm.d.rv1[tid], a2 = sm.d.rv2[tid]; int c1 = sm.d.ri1[tid], c2 = sm.d.ri2[tid];
      top2_merge(a1, c1, a2, c2, sm.d.rv1[tid + off], sm.d.ri1[tid + off],
                 sm.d.rv2[tid + off], sm.d.ri2[tid + off]);
      sm.d.rv1[tid] = a1; sm.d.ri1[tid] = c1; sm.d.rv2[tid] = a2; sm.d.ri2[tid] = c2;
    }
    __syncthreads();
  }
  const int I1 = sm.d.ri1[0], I2 = sm.d.ri2[0];
  const float lse = sm.d.rm[0] + logf(sm.d.rs[0]);
  const float* e1 = emb + (size_t)I1 * EMBN;
  const float* e2 = emb + (size_t)I2 * EMBN;
  const float* hb = h1f + b * EMBN;
  if (tid < 512) {
    float hv = hb[tid];
    sm.d.s1[tid] = e1[tid] * hv;
    sm.d.s2[tid] = e2[tid] * hv;
  }
  __syncthreads();
  for (int off = 256; off > 0; off >>= 1) {
    if (tid < off) { sm.d.s1[tid] += sm.d.s1[tid + off]; sm.d.s2[tid] += sm.d.s2[tid + off]; }
    __syncthreads();
  }
  const float d1 = sm.d.s1[0], d2 = sm.d.s2[0];
  const float x1 = d1 + gum_t[(size_t)b * VOC + I1];
  const float x2 = d2 + gum_t[(size_t)b * VOC + I2];
  int tok; float dsel;
  if (x2 > x1 || (x2 == x1 && I2 < I1)) { tok = I2; dsel = d2; }
  else                                  { tok = I1; dsel = d1; }
  if (tid < 512) {
    float ev = emb[(size_t)tok * EMBN + tid];
    unsigned short hv = f2bf(ev);
    xhi[b * EMBN + tid] = hv;
    xlo[b * EMBN + tid] = f2bf(ev - bf2f(hv));
  }
  if (tid == 0) {
    out[b * TSTEPS + t] = (float)tok;
    out[BATCH * TSTEPS + b * TSTEPS + t] = dsel - lse;
  }
}

// ================= persistent decode kernel: 256 blocks x 1024 threads =================
__global__ __launch_bounds__(1024, 4) void k_persist(
    const unsigned short* __restrict__ embbf, const float* __restrict__ emb,
    const float* __restrict__ gum, const unsigned short* __restrict__ wg,
    const float* __restrict__ b_l, float* __restrict__ hbuf, float* __restrict__ cbuf,
    unsigned short* __restrict__ xhi, unsigned short* __restrict__ xlo,
    unsigned short* __restrict__ hshi, unsigned short* __restrict__ hslo,
    float* __restrict__ red, float* __restrict__ out, unsigned* __restrict__ bar) {
  __shared__ Smem sm;
  const int blk = blockIdx.x, tid = threadIdx.x;
  const size_t HS = (size_t)BATCH * HID;   // per (parity,layer) slot

  for (int t = 0; t < TSTEPS; ++t) {
    const float* gum_t = gum + (size_t)t * BATCH * VOC;
    const int p = t & 1, q = p ^ 1;
    if (blk < 8) {
      // phase A: layer 0 (x, h0[p] -> h0[q])
      lstm_block(0, blk, tid, xhi, xlo,
                 hshi + ((size_t)p * 2 + 0) * HS, hslo + ((size_t)p * 2 + 0) * HS,
                 wg, b_l, hbuf, cbuf,
                 hshi + ((size_t)q * 2 + 0) * HS, hslo + ((size_t)q * 2 + 0) * HS, sm);
      minibar(bar);
      // phase B: layer 1 (h0[q], h1[p] -> h1[q])
      lstm_block(1, blk, tid,
                 hshi + ((size_t)q * 2 + 0) * HS, hslo + ((size_t)q * 2 + 0) * HS,
                 hshi + ((size_t)p * 2 + 1) * HS, hslo + ((size_t)p * 2 + 1) * HS,
                 wg, b_l, hbuf, cbuf,
                 hshi + ((size_t)q * 2 + 1) * HS, hslo + ((size_t)q * 2 + 1) * HS, sm);
      prefetch_tile(blk, tid, embbf, gum_t);
    } else if (blk < NVT) {
      prefetch_tile(blk, tid, embbf, gum_t);   // warm own L2 while LSTM runs
    }
    fullbar(bar);
    // phase C: logits + LSE + top-2 screening
    if (blk < NVT)
      logits_block(blk, tid, embbf, hshi + ((size_t)q * 2 + 1) * HS, gum_t, red, sm);
    fullbar(bar);
    // phase D: final reduce + exact rescore + sample
    if (blk < BATCH)
      sample_block(blk, tid, t, red, emb, hbuf + HS, gum_t, xhi, xlo, out, sm);
    fullbar(bar);
  }
}

}  // namespace

extern "C" void kernel_launch(void* const* d_in, const int* in_sizes, int n_in,
                              void* d_out, int out_size, void* d_ws, size_t ws_size,
                              hipStream_t stream) {
  const float* img  = (const float*)d_in[0];
  const float* W_fh = (const float*)d_in[1];
  const float* b_fh = (const float*)d_in[2];
  const float* Wc   = (const float*)d_in[3];
  const float* bc   = (const float*)d_in[4];
  const float* Wh   = (const float*)d_in[5];
  const float* bh   = (const float*)d_in[6];
  const float* W_ih = (const float*)d_in[7];
  const float* W_hh = (const float*)d_in[8];
  const float* b_l  = (const float*)d_in[9];
  const float* emb  = (const float*)d_in[10];
  const float* gum  = (const float*)d_in[11];
  float* out = (float*)d_out;

  float* w     = (float*)d_ws;
  float* femb  = w;                                    // 3136*512
  float* fmean = femb + (size_t)3136 * 512;            // 64*512
  float* hbuf  = fmean + 64 * 512;                     // 2*64*512 f32
  float* cbuf  = hbuf + 2 * 64 * 512;                  // 2*64*512 f32
  float* red   = cbuf + 2 * 64 * 512;                  // 250*64*8
  unsigned* bar = (unsigned*)(red + 250 * 64 * 8);     // 512 uints

  unsigned short* us = (unsigned short*)(bar + 512);
  unsigned short* embbf  = us;                                  // 32000*512
  unsigned short* imghi  = embbf + (size_t)VOC * EMBN;          // 3136*2048
  unsigned short* imglo  = imghi + (size_t)3136 * 2048;
  unsigned short* wfh_hi = imglo + (size_t)3136 * 2048;         // 512*2048 (W_fh^T)
  unsigned short* wfh_lo = wfh_hi + (size_t)512 * 2048;
  unsigned short* wg     = wfh_lo + (size_t)512 * 2048;         // [l][mat][hi/lo][2048][512]
  const size_t WGM = (size_t)G4 * 512;
  unsigned short* xhi    = wg + 8 * WGM;                        // 64*512
  unsigned short* xlo    = xhi + 64 * 512;
  unsigned short* hshi   = xlo + 64 * 512;                      // [2 parity][2 layer][64][512]
  unsigned short* hslo   = hshi + (size_t)4 * 64 * 512;

  auto wgp = [&](int l, int mat, int part_) -> unsigned short* {
    return wg + (((size_t)l * 2 + mat) * 2 + part_) * WGM;
  };

  // ---- one-time prep ----
  k_emb2bf<<<8000, 256, 0, stream>>>(emb, embbf);
  k_split<<<3136 * 2048 / 8 / 256, 256, 0, stream>>>(img, imghi, imglo);
  k_trans<<<dim3(FEATN / 32, FHN / 32), 256, 0, stream>>>(W_fh, wfh_hi, wfh_lo, FEATN, FHN);
  for (int l = 0; l < 2; ++l) {
    k_trans<<<dim3(EMBN / 32, G4 / 32), 256, 0, stream>>>(W_ih + (size_t)l * EMBN * G4, wgp(l, 0, 0), wgp(l, 0, 1), EMBN, G4);
    k_trans<<<dim3(HID / 32, G4 / 32), 256, 0, stream>>>(W_hh + (size_t)l * HID * G4, wgp(l, 1, 0), wgp(l, 1, 1), HID, G4);
  }
  k_feat_mfma<<<dim3(49, 8), 256, 0, stream>>>(imghi, imglo, wfh_hi, wfh_lo, b_fh, femb);
  k_mean<<<128, 256, 0, stream>>>(femb, fmean);
  k_h0c0<<<dim3(8, 2, 2), 256, 0, stream>>>(fmean, Wc, bc, Wh, bh, hbuf, cbuf, hshi, hslo);
  k_initx<<<128, 256, 0, stream>>>(xhi, xlo);
  k_zero<<<1, 512, 0, stream>>>(bar);

  // ---- persistent 40-step decode: 256 blocks x 1024 threads (16 waves/CU) ----
  k_persist<<<NBLK, 1024, 0, stream>>>(embbf, emb, gum, wg, b_l, hbuf, cbuf,
                                       xhi, xlo, hshi, hslo, red, out, bar);
}

// Round 6
// 9048.878 us; speedup vs baseline: 1.7429x; 1.7429x over previous
//
#include <hip/hip_runtime.h>
#include <cmath>

namespace {

constexpr int BATCH = 64;
constexpr int NREG  = 49;
constexpr int FEATN = 2048;
constexpr int FHN   = 512;
constexpr int HID   = 512;
constexpr int EMBN  = 512;
constexpr int VOC   = 32000;
constexpr int TSTEPS= 40;
constexpr int G4    = 2048;       // 4*H
constexpr int NVT   = VOC / 128;  // 250 v-tiles for logits
constexpr int NBLK  = 256;        // persistent grid (1 block/CU)

typedef short bf16x8 __attribute__((ext_vector_type(8)));
typedef float f32x4  __attribute__((ext_vector_type(4)));

__device__ __forceinline__ float sigm(float x) { return 1.0f / (1.0f + expf(-x)); }

__device__ __forceinline__ unsigned short f2bf(float f) {
  unsigned u = __float_as_uint(f);
  unsigned r = (u + 0x7fffu + ((u >> 16) & 1u)) >> 16;   // RNE
  return (unsigned short)r;
}
__device__ __forceinline__ float bf2f(unsigned short h) {
  return __uint_as_float(((unsigned)h) << 16);
}

__device__ __forceinline__ bool better(float a, int ia, float b, int ib) {
  return a > b || (a == b && ia < ib);
}
__device__ __forceinline__ void top2_merge(float& v1, int& i1, float& v2, int& i2,
                                           float u1, int j1, float u2, int j2) {
  if (better(u1, j1, v1, i1)) {
    float t = v1; int ti = i1;
    v1 = u1; i1 = j1;
    if (better(u2, j2, t, ti)) { v2 = u2; i2 = j2; } else { v2 = t; i2 = ti; }
  } else {
    if (better(u1, j1, v2, i2)) { v2 = u1; i2 = j1; }
  }
}
__device__ __forceinline__ void lse_merge(float& m, float& s, float om, float os) {
  float nm = fmaxf(m, om);
  float ns = 0.f;
  if (m  > -INFINITY) ns += s  * expf(m  - nm);
  if (om > -INFINITY) ns += os * expf(om - nm);
  m = nm; s = ns;
}

// ================= shared memory: persistent emb tile + phase union =================
struct Smem {
  unsigned short embl[128 * 512];            // 128KB, XOR-swizzled rows, PERSISTENT all 40 steps
  union {
    float gs[4][64][16];                     // LSTM gate scratch (16KB)
    struct {                                 // phase C reduction (12KB)
      float rm[512], rs[512], rv1[512], rv2[512];
      int   ri1[512], ri2[512];
    } c;
    struct {                                 // phase D (10KB)
      float rm[256], rs[256], rv1[256], rv2[256];
      int   ri1[256], ri2[256];
      float s1[512], s2[512];
    } d;
  } u;
};                                           // 147456 B total -> 1 block/CU

// ================= barriers (same structure as r4/r5 which passed) =================
// bar: shard counters at 32*s (s=0..7), master 288, gen 320, mini counter 352, mini gen 384
__device__ __forceinline__ void fullbar(unsigned* bar) {
  __syncthreads();
  if (threadIdx.x == 0) {
    __threadfence();
    unsigned gen = __hip_atomic_load(bar + 320, __ATOMIC_RELAXED, __HIP_MEMORY_SCOPE_AGENT);
    const int shard = blockIdx.x & 7;
    unsigned a = __hip_atomic_fetch_add(bar + shard * 32, 1u, __ATOMIC_ACQ_REL, __HIP_MEMORY_SCOPE_AGENT);
    if (a == 31u) {
      __hip_atomic_store(bar + shard * 32, 0u, __ATOMIC_RELAXED, __HIP_MEMORY_SCOPE_AGENT);
      unsigned m = __hip_atomic_fetch_add(bar + 288, 1u, __ATOMIC_ACQ_REL, __HIP_MEMORY_SCOPE_AGENT);
      if (m == 7u) {
        __hip_atomic_store(bar + 288, 0u, __ATOMIC_RELAXED, __HIP_MEMORY_SCOPE_AGENT);
        __hip_atomic_fetch_add(bar + 320, 1u, __ATOMIC_RELEASE, __HIP_MEMORY_SCOPE_AGENT);
      }
    }
    while (__hip_atomic_load(bar + 320, __ATOMIC_RELAXED, __HIP_MEMORY_SCOPE_AGENT) == gen)
      __builtin_amdgcn_s_sleep(2);
    __threadfence();
  }
  __syncthreads();
}

__device__ __forceinline__ void minibar(unsigned* bar) {   // LSTM blocks 0..31 only
  __syncthreads();
  if (threadIdx.x == 0) {
    __threadfence();
    unsigned gen = __hip_atomic_load(bar + 384, __ATOMIC_RELAXED, __HIP_MEMORY_SCOPE_AGENT);
    unsigned a = __hip_atomic_fetch_add(bar + 352, 1u, __ATOMIC_ACQ_REL, __HIP_MEMORY_SCOPE_AGENT);
    if (a == 31u) {
      __hip_atomic_store(bar + 352, 0u, __ATOMIC_RELAXED, __HIP_MEMORY_SCOPE_AGENT);
      __hip_atomic_fetch_add(bar + 384, 1u, __ATOMIC_RELEASE, __HIP_MEMORY_SCOPE_AGENT);
    }
    while (__hip_atomic_load(bar + 384, __ATOMIC_RELAXED, __HIP_MEMORY_SCOPE_AGENT) == gen)
      __builtin_amdgcn_s_sleep(1);
    __threadfence();
  }
  __syncthreads();
}

// ================= prep kernels (one-time, unchanged from r3-r5) =================

__global__ __launch_bounds__(256) void k_trans(const float* __restrict__ src,
    unsigned short* __restrict__ dhi, unsigned short* __restrict__ dlo, int K, int N) {
  __shared__ float tile[32][33];
  const int k0 = blockIdx.x * 32, n0 = blockIdx.y * 32;
  const int tx = threadIdx.x & 31, ty = threadIdx.x >> 5;
#pragma unroll
  for (int r = ty; r < 32; r += 8) tile[r][tx] = src[(size_t)(k0 + r) * N + n0 + tx];
  __syncthreads();
#pragma unroll
  for (int r = ty; r < 32; r += 8) {
    float v = tile[tx][r];
    unsigned short hv = f2bf(v);
    size_t o = (size_t)(n0 + r) * K + k0 + tx;
    dhi[o] = hv;
    dlo[o] = f2bf(v - bf2f(hv));
  }
}

__global__ void k_split(const float* __restrict__ src, unsigned short* __restrict__ dhi,
                        unsigned short* __restrict__ dlo) {
  const size_t i = (size_t)blockIdx.x * 256 + threadIdx.x;
  const float4* p = reinterpret_cast<const float4*>(src) + i * 2;
  float4 a = p[0], b = p[1];
  float v[8] = {a.x, a.y, a.z, a.w, b.x, b.y, b.z, b.w};
  unsigned short hi[8], lo[8];
#pragma unroll
  for (int j = 0; j < 8; ++j) {
    hi[j] = f2bf(v[j]);
    lo[j] = f2bf(v[j] - bf2f(hi[j]));
  }
  uint4 oh, ol;
  oh.x = hi[0] | (hi[1] << 16); oh.y = hi[2] | (hi[3] << 16);
  oh.z = hi[4] | (hi[5] << 16); oh.w = hi[6] | (hi[7] << 16);
  ol.x = lo[0] | (lo[1] << 16); ol.y = lo[2] | (lo[3] << 16);
  ol.z = lo[4] | (lo[5] << 16); ol.w = lo[6] | (lo[7] << 16);
  reinterpret_cast<uint4*>(dhi)[i] = oh;
  reinterpret_cast<uint4*>(dlo)[i] = ol;
}

__global__ void k_emb2bf(const float* __restrict__ emb, unsigned short* __restrict__ ebf) {
  const size_t i = (size_t)blockIdx.x * 256 + threadIdx.x;
  const float4* p = reinterpret_cast<const float4*>(emb) + i * 2;
  float4 a = p[0], b = p[1];
  uint4 o;
  o.x = (unsigned)f2bf(a.x) | ((unsigned)f2bf(a.y) << 16);
  o.y = (unsigned)f2bf(a.z) | ((unsigned)f2bf(a.w) << 16);
  o.z = (unsigned)f2bf(b.x) | ((unsigned)f2bf(b.y) << 16);
  o.w = (unsigned)f2bf(b.z) | ((unsigned)f2bf(b.w) << 16);
  reinterpret_cast<uint4*>(ebf)[i] = o;
}

__global__ __launch_bounds__(256) void k_feat_mfma(
    const unsigned short* __restrict__ Ahi, const unsigned short* __restrict__ Alo,
    const unsigned short* __restrict__ Bhi, const unsigned short* __restrict__ Blo,
    const float* __restrict__ bias, float* __restrict__ femb) {
  const int m0 = blockIdx.x * 64, n0 = blockIdx.y * 64;
  const int tid = threadIdx.x, lane = tid & 63, w = tid >> 6;
  const int l15 = lane & 15, l4 = lane >> 4;
  f32x4 acc[4];
#pragma unroll
  for (int nt = 0; nt < 4; ++nt) acc[nt] = (f32x4){0.f, 0.f, 0.f, 0.f};
  const size_t arow = (size_t)(m0 + w * 16 + l15) * FEATN;
  for (int kk = 0; kk < FEATN / 32; ++kk) {
    const int k = kk * 32 + l4 * 8;
    bf16x8 a1 = *reinterpret_cast<const bf16x8*>(Ahi + arow + k);
    bf16x8 a2 = *reinterpret_cast<const bf16x8*>(Alo + arow + k);
#pragma unroll
    for (int nt = 0; nt < 4; ++nt) {
      const size_t brow = (size_t)(n0 + nt * 16 + l15) * FEATN + k;
      bf16x8 b1 = *reinterpret_cast<const bf16x8*>(Bhi + brow);
      bf16x8 b2 = *reinterpret_cast<const bf16x8*>(Blo + brow);
      acc[nt] = __builtin_amdgcn_mfma_f32_16x16x32_bf16(a1, b1, acc[nt], 0, 0, 0);
      acc[nt] = __builtin_amdgcn_mfma_f32_16x16x32_bf16(a1, b2, acc[nt], 0, 0, 0);
      acc[nt] = __builtin_amdgcn_mfma_f32_16x16x32_bf16(a2, b1, acc[nt], 0, 0, 0);
    }
  }
#pragma unroll
  for (int nt = 0; nt < 4; ++nt)
#pragma unroll
    for (int i = 0; i < 4; ++i) {
      int m = m0 + w * 16 + l4 * 4 + i, n = n0 + nt * 16 + l15;
      femb[(size_t)m * FHN + n] = tanhf(acc[nt][i] + bias[n]);
    }
}

__global__ void k_mean(const float* __restrict__ femb, float* __restrict__ fmean) {
  const int gid = blockIdx.x * 256 + threadIdx.x;  // 32768
  const int b = gid >> 9, f = gid & 511;
  float s = 0.f;
  for (int n = 0; n < NREG; ++n) s += femb[(size_t)(b * NREG + n) * FHN + f];
  fmean[gid] = s * (1.0f / NREG);
}

__global__ __launch_bounds__(256) void k_h0c0(const float* __restrict__ fmean,
    const float* __restrict__ Wc, const float* __restrict__ bc,
    const float* __restrict__ Wh, const float* __restrict__ bh,
    float* __restrict__ hbuf, float* __restrict__ cbuf,
    unsigned short* __restrict__ hshi, unsigned short* __restrict__ hslo) {
  const int n0 = blockIdx.x * 64, l = blockIdx.y, isH = blockIdx.z;
  const float* W   = (isH ? Wh : Wc) + (size_t)l * FHN * HID;
  const float* bias= (isH ? bh : bc) + l * HID;
  float* outp      = (isH ? hbuf : cbuf) + (size_t)l * BATCH * HID;
  __shared__ float As[16][68], Bs[16][68];
  const int tid = threadIdx.x, tx = tid & 15, ty = tid >> 4;
  float acc[4][4] = {};
  for (int k0 = 0; k0 < FHN; k0 += 16) {
#pragma unroll
    for (int e = 0; e < 4; ++e) { int idx = tid + e * 256, m = idx >> 4, k = idx & 15; As[k][m] = fmean[m * FHN + k0 + k]; }
#pragma unroll
    for (int e = 0; e < 4; ++e) { int idx = tid + e * 256, k = idx >> 6, n = idx & 63; Bs[k][n] = W[(size_t)(k0 + k) * HID + n0 + n]; }
    __syncthreads();
#pragma unroll
    for (int k = 0; k < 16; ++k) {
      float4 av = *(const float4*)&As[k][ty * 4];
      float4 bv = *(const float4*)&Bs[k][tx * 4];
      float a[4] = {av.x, av.y, av.z, av.w}, b[4] = {bv.x, bv.y, bv.z, bv.w};
#pragma unroll
      for (int i = 0; i < 4; ++i)
#pragma unroll
        for (int j = 0; j < 4; ++j) acc[i][j] = fmaf(a[i], b[j], acc[i][j]);
    }
    __syncthreads();
  }
#pragma unroll
  for (int i = 0; i < 4; ++i) {
    int m = ty * 4 + i, n = n0 + tx * 4;
    float vals[4];
#pragma unroll
    for (int j = 0; j < 4; ++j) vals[j] = acc[i][j] + bias[n + j];
    *(float4*)&outp[(size_t)m * HID + n] = make_float4(vals[0], vals[1], vals[2], vals[3]);
    if (isH) {
#pragma unroll
      for (int j = 0; j < 4; ++j) {
        unsigned short hv = f2bf(vals[j]);
        size_t o = (size_t)l * BATCH * HID + (size_t)m * HID + n + j;  // parity-0 slot
        hshi[o] = hv;
        hslo[o] = f2bf(vals[j] - bf2f(hv));
      }
    }
  }
}

__global__ void k_initx(unsigned short* __restrict__ xhi, unsigned short* __restrict__ xlo) {
  const int i = blockIdx.x * 256 + threadIdx.x;
  xhi[i] = 0x4040; xlo[i] = 0;      // 3.0 exact in bf16
}

__global__ void k_zero(unsigned* __restrict__ bar) {
  bar[threadIdx.x] = 0;             // 512 uints
}

// ================= persistent-kernel phase bodies =================

// ---- LSTM layer: 32 blocks; block bl covers cols [bl*16, bl*16+16) of all 4 gates.
//      wave w: gate g = w>>2, m-tile mt = w&3.
__device__ __forceinline__ void lstm_block(int l, int bl, int tid,
    const unsigned short* __restrict__ xh, const unsigned short* __restrict__ xl,
    const unsigned short* __restrict__ hh, const unsigned short* __restrict__ hlo_,
    const unsigned short* __restrict__ wg, const float* __restrict__ bl_,
    float* __restrict__ hbuf, float* __restrict__ cbuf,
    unsigned short* __restrict__ ho_hi, unsigned short* __restrict__ ho_lo,
    Smem& sm) {
  const int lane = tid & 63, w = tid >> 6;
  const int l15 = lane & 15, l4 = lane >> 4;
  const int g = w >> 2, mt = w & 3;
  const size_t WGM = (size_t)G4 * 512;
  const unsigned short* wih_hi = wg + (((size_t)l * 2 + 0) * 2 + 0) * WGM;
  const unsigned short* wih_lo = wih_hi + WGM;
  const unsigned short* whh_hi = wg + (((size_t)l * 2 + 1) * 2 + 0) * WGM;
  const unsigned short* whh_lo = whh_hi + WGM;
  const size_t nrow = (size_t)(g * 512 + bl * 16 + l15) * 512;
  const size_t arow = (size_t)(mt * 16 + l15) * 512;
  f32x4 acc = (f32x4){0.f, 0.f, 0.f, 0.f};
#pragma unroll
  for (int ks = 0; ks < 16; ++ks) {          // x @ Wih
    const int k = ks * 32 + l4 * 8;
    bf16x8 b1 = *reinterpret_cast<const bf16x8*>(wih_hi + nrow + k);
    bf16x8 b2 = *reinterpret_cast<const bf16x8*>(wih_lo + nrow + k);
    bf16x8 a1 = *reinterpret_cast<const bf16x8*>(xh + arow + k);
    bf16x8 a2 = *reinterpret_cast<const bf16x8*>(xl + arow + k);
    acc = __builtin_amdgcn_mfma_f32_16x16x32_bf16(a1, b1, acc, 0, 0, 0);
    acc = __builtin_amdgcn_mfma_f32_16x16x32_bf16(a1, b2, acc, 0, 0, 0);
    acc = __builtin_amdgcn_mfma_f32_16x16x32_bf16(a2, b1, acc, 0, 0, 0);
  }
#pragma unroll
  for (int ks = 0; ks < 16; ++ks) {          // h @ Whh
    const int k = ks * 32 + l4 * 8;
    bf16x8 b1 = *reinterpret_cast<const bf16x8*>(whh_hi + nrow + k);
    bf16x8 b2 = *reinterpret_cast<const bf16x8*>(whh_lo + nrow + k);
    bf16x8 a1 = *reinterpret_cast<const bf16x8*>(hh + arow + k);
    bf16x8 a2 = *reinterpret_cast<const bf16x8*>(hlo_ + arow + k);
    acc = __builtin_amdgcn_mfma_f32_16x16x32_bf16(a1, b1, acc, 0, 0, 0);
    acc = __builtin_amdgcn_mfma_f32_16x16x32_bf16(a1, b2, acc, 0, 0, 0);
    acc = __builtin_amdgcn_mfma_f32_16x16x32_bf16(a2, b1, acc, 0, 0, 0);
  }
#pragma unroll
  for (int i = 0; i < 4; ++i)
    sm.u.gs[g][mt * 16 + l4 * 4 + i][l15] = acc[i];
  __syncthreads();
  {                                          // cell: one per thread (64 b x 16 j)
    const int b = tid >> 4, jl = tid & 15, j = bl * 16 + jl;
    float gi = sm.u.gs[0][b][jl] + bl_[l * 2048 + j];
    float gf = sm.u.gs[1][b][jl] + bl_[l * 2048 + 512 + j];
    float gg = sm.u.gs[2][b][jl] + bl_[l * 2048 + 1024 + j];
    float go = sm.u.gs[3][b][jl] + bl_[l * 2048 + 1536 + j];
    const size_t o = (size_t)l * BATCH * HID + (size_t)b * HID + j;
    float cn = sigm(gf) * cbuf[o] + sigm(gi) * tanhf(gg);
    float hn = sigm(go) * tanhf(cn);
    cbuf[o] = cn; hbuf[o] = hn;
    unsigned short hv = f2bf(hn);
    ho_hi[b * HID + j] = hv; ho_lo[b * HID + j] = f2bf(hn - bf2f(hv));
  }
  __syncthreads();
}

// ---- logits tile: A-frags from persistent LDS emb tile; gumbel from pre-loaded regs ----
__device__ __forceinline__ void logits_block(int blk, int tid,
    const unsigned short* __restrict__ h1hi, const float4 gr0, const float4 gr1,
    float* __restrict__ red, Smem& sm) {
  const int v0 = blk * 128;
  const int lane = tid & 63, w = tid >> 6;
  const int l15 = lane & 15, l4 = lane >> 4;
  const int vsub = w >> 1, bhalf = w & 1;
  const int arow = vsub * 16 + l15;
  const char* abase = reinterpret_cast<const char*>(sm.embl) + arow * 1024;
  const int axor = (arow & 7) << 4;

  f32x4 acc[2];
  acc[0] = (f32x4){0.f, 0.f, 0.f, 0.f};
  acc[1] = (f32x4){0.f, 0.f, 0.f, 0.f};
#pragma unroll
  for (int ks = 0; ks < 16; ++ks) {
    bf16x8 a0 = *reinterpret_cast<const bf16x8*>(abase + ((ks * 64 + l4 * 16) ^ axor));
#pragma unroll
    for (int nl = 0; nl < 2; ++nl) {
      const int brow = (bhalf * 2 + nl) * 16 + l15;
      bf16x8 bb = *reinterpret_cast<const bf16x8*>(h1hi + (size_t)brow * 512 + ks * 32 + l4 * 8);
      acc[nl] = __builtin_amdgcn_mfma_f32_16x16x32_bf16(a0, bb, acc[nl], 0, 0, 0);
    }
  }

  const int vb = v0 + vsub * 16 + l4 * 4;
#pragma unroll
  for (int nl = 0; nl < 2; ++nl) {
    const float4 g0 = nl ? gr1 : gr0;
    float lg[4] = {acc[nl][0], acc[nl][1], acc[nl][2], acc[nl][3]};
    float gv[4] = {g0.x, g0.y, g0.z, g0.w};
    float mx = fmaxf(fmaxf(lg[0], lg[1]), fmaxf(lg[2], lg[3]));
    float ss = 0.f;
    float v1 = -INFINITY, v2 = -INFINITY; int i1 = 0x7fffffff, i2 = 0x7fffffff;
#pragma unroll
    for (int i = 0; i < 4; ++i) {
      ss += expf(lg[i] - mx);
      float val = lg[i] + gv[i];
      int idx = vb + i;
      if (better(val, idx, v1, i1)) { v2 = v1; i2 = i1; v1 = val; i1 = idx; }
      else if (better(val, idx, v2, i2)) { v2 = val; i2 = idx; }
    }
#pragma unroll
    for (int mask = 16; mask <= 32; mask <<= 1) {
      float om = __shfl_xor(mx, mask);
      float os = __shfl_xor(ss, mask);
      float u1 = __shfl_xor(v1, mask); int j1 = __shfl_xor(i1, mask);
      float u2 = __shfl_xor(v2, mask); int j2 = __shfl_xor(i2, mask);
      lse_merge(mx, ss, om, os);
      top2_merge(v1, i1, v2, i2, u1, j1, u2, j2);
    }
    if (lane < 16) {
      int slot = (w * 2 + nl) * 16 + l15;
      sm.u.c.rm[slot] = mx; sm.u.c.rs[slot] = ss;
      sm.u.c.rv1[slot] = v1; sm.u.c.ri1[slot] = i1; sm.u.c.rv2[slot] = v2; sm.u.c.ri2[slot] = i2;
    }
  }
  __syncthreads();
  if (tid < 64) {
    const int b = tid, bh = b >> 5, nl = (b >> 4) & 1, c = b & 15;
    int s0 = (bh * 2 + nl) * 16 + c;             // vsub = 0
    float M = sm.u.c.rm[s0], S = sm.u.c.rs[s0], V1 = sm.u.c.rv1[s0], V2 = sm.u.c.rv2[s0];
    int I1 = sm.u.c.ri1[s0], I2 = sm.u.c.ri2[s0];
#pragma unroll
    for (int vs = 1; vs < 8; ++vs) {
      int sl = ((vs * 2 + bh) * 2 + nl) * 16 + c;
      lse_merge(M, S, sm.u.c.rm[sl], sm.u.c.rs[sl]);
      top2_merge(V1, I1, V2, I2, sm.u.c.rv1[sl], sm.u.c.ri1[sl], sm.u.c.rv2[sl], sm.u.c.ri2[sl]);
    }
    float* rp = red + ((size_t)blk * 64 + tid) * 8;
    rp[0] = M; rp[1] = S;
    rp[2] = V1; rp[3] = __int_as_float(I1);
    rp[4] = V2; rp[5] = __int_as_float(I2);
  }
}

// ---- final reduce + exact f32 rescore + sample ----
__device__ __forceinline__ void sample_block(int b, int tid, int t,
    const float* __restrict__ red, const float* __restrict__ emb,
    const float* __restrict__ h1f, const float* __restrict__ gum_t,
    unsigned short* __restrict__ xhi, unsigned short* __restrict__ xlo,
    float* __restrict__ out, Smem& sm) {
  if (tid < 256) {
    float m = -INFINITY, s = 0.f, v1 = -INFINITY, v2 = -INFINITY;
    int i1 = 0x7fffffff, i2 = 0x7fffffff;
    if (tid < NVT) {
      const float* rp = red + ((size_t)tid * 64 + b) * 8;
      m = rp[0]; s = rp[1];
      v1 = rp[2]; i1 = __float_as_int(rp[3]);
      v2 = rp[4]; i2 = __float_as_int(rp[5]);
    }
    sm.u.d.rm[tid] = m; sm.u.d.rs[tid] = s;
    sm.u.d.rv1[tid] = v1; sm.u.d.ri1[tid] = i1; sm.u.d.rv2[tid] = v2; sm.u.d.ri2[tid] = i2;
  }
  __syncthreads();
  for (int off = 128; off > 0; off >>= 1) {
    if (tid < off) {
      float M = sm.u.d.rm[tid], S = sm.u.d.rs[tid];
      lse_merge(M, S, sm.u.d.rm[tid + off], sm.u.d.rs[tid + off]);
      sm.u.d.rm[tid] = M; sm.u.d.rs[tid] = S;
      float a1 = sm.u.d.rv1[tid], a2 = sm.u.d.rv2[tid]; int c1 = sm.u.d.ri1[tid], c2 = sm.u.d.ri2[tid];
      top2_merge(a1, c1, a2, c2, sm.u.d.rv1[tid + off], sm.u.d.ri1[tid + off],
                 sm.u.d.rv2[tid + off], sm.u.d.ri2[tid + off]);
      sm.u.d.rv1[tid] = a1; sm.u.d.ri1[tid] = c1; sm.u.d.rv2[tid] = a2; sm.u.d.ri2[tid] = c2;
    }
    __syncthreads();
  }
  const int I1 = sm.u.d.ri1[0], I2 = sm.u.d.ri2[0];
  const float lse = sm.u.d.rm[0] + logf(sm.u.d.rs[0]);
  const float* e1 = emb + (size_t)I1 * EMBN;
  const float* e2 = emb + (size_t)I2 * EMBN;
  const float* hb = h1f + b * EMBN;
  if (tid < 512) {
    float hv = hb[tid];
    sm.u.d.s1[tid] = e1[tid] * hv;
    sm.u.d.s2[tid] = e2[tid] * hv;
  }
  __syncthreads();
  for (int off = 256; off > 0; off >>= 1) {
    if (tid < off) { sm.u.d.s1[tid] += sm.u.d.s1[tid + off]; sm.u.d.s2[tid] += sm.u.d.s2[tid + off]; }
    __syncthreads();
  }
  const float d1 = sm.u.d.s1[0], d2 = sm.u.d.s2[0];
  const float x1 = d1 + gum_t[(size_t)b * VOC + I1];
  const float x2 = d2 + gum_t[(size_t)b * VOC + I2];
  int tok; float dsel;
  if (x2 > x1 || (x2 == x1 && I2 < I1)) { tok = I2; dsel = d2; }
  else                                  { tok = I1; dsel = d1; }
  if (tid < 512) {
    float ev = emb[(size_t)tok * EMBN + tid];
    unsigned short hv = f2bf(ev);
    xhi[b * EMBN + tid] = hv;
    xlo[b * EMBN + tid] = f2bf(ev - bf2f(hv));
  }
  if (tid == 0) {
    out[b * TSTEPS + t] = (float)tok;
    out[BATCH * TSTEPS + b * TSTEPS + t] = dsel - lse;
  }
}

// ================= persistent decode kernel: 256 blocks x 1024 threads =================
__global__ __launch_bounds__(1024, 4) void k_persist(
    const unsigned short* __restrict__ embbf, const float* __restrict__ emb,
    const float* __restrict__ gum, const unsigned short* __restrict__ wg,
    const float* __restrict__ b_l, float* __restrict__ hbuf, float* __restrict__ cbuf,
    unsigned short* __restrict__ xhi, unsigned short* __restrict__ xlo,
    unsigned short* __restrict__ hshi, unsigned short* __restrict__ hslo,
    float* __restrict__ red, float* __restrict__ out, unsigned* __restrict__ bar) {
  __shared__ Smem sm;
  const int blk = blockIdx.x, tid = threadIdx.x;
  const size_t HS = (size_t)BATCH * HID;   // per (parity,layer) slot
  const int lane = tid & 63, w = tid >> 6;
  const int l15 = lane & 15, l4 = lane >> 4;

  // ---- one-time: stage this block's emb v-tile into LDS (persistent, XOR-swizzled) ----
  if (blk < NVT) {
    const uint4* ep = reinterpret_cast<const uint4*>(embbf + (size_t)blk * 128 * 512);
#pragma unroll
    for (int i = 0; i < 8; ++i) {
      int c = tid + i * 1024;              // 16B chunk, 8192 total (64 per row)
      int row = c >> 6;
      int inb = (c & 63) << 4;
      uint4 v = ep[c];
      int sw = inb ^ ((row & 7) << 4);
      *reinterpret_cast<uint4*>(reinterpret_cast<char*>(sm.embl) + row * 1024 + sw) = v;
    }
  }
  __syncthreads();

  for (int t = 0; t < TSTEPS; ++t) {
    const float* gum_t = gum + (size_t)t * BATCH * VOC;
    const int p = t & 1, q = p ^ 1;

    // pre-load this thread's phase-C gumbel values (depends only on t) -> in flight
    // across the LSTM phase + barrier
    float4 gr0 = make_float4(0.f, 0.f, 0.f, 0.f), gr1 = gr0;
    if (blk < NVT) {
      const int vb_ = blk * 128 + (w >> 1) * 16 + l4 * 4;
      const int b0 = ((w & 1) * 2 + 0) * 16 + l15;
      const int b1 = ((w & 1) * 2 + 1) * 16 + l15;
      gr0 = *reinterpret_cast<const float4*>(gum_t + (size_t)b0 * VOC + vb_);
      gr1 = *reinterpret_cast<const float4*>(gum_t + (size_t)b1 * VOC + vb_);
    }

    if (blk < 32) {
      // phase A: layer 0 (x, h0[p] -> h0[q])
      lstm_block(0, blk, tid, xhi, xlo,
                 hshi + ((size_t)p * 2 + 0) * HS, hslo + ((size_t)p * 2 + 0) * HS,
                 wg, b_l, hbuf, cbuf,
                 hshi + ((size_t)q * 2 + 0) * HS, hslo + ((size_t)q * 2 + 0) * HS, sm);
      minibar(bar);
      // phase B: layer 1 (h0[q], h1[p] -> h1[q])
      lstm_block(1, blk, tid,
                 hshi + ((size_t)q * 2 + 0) * HS, hslo + ((size_t)q * 2 + 0) * HS,
                 hshi + ((size_t)p * 2 + 1) * HS, hslo + ((size_t)p * 2 + 1) * HS,
                 wg, b_l, hbuf, cbuf,
                 hshi + ((size_t)q * 2 + 1) * HS, hslo + ((size_t)q * 2 + 1) * HS, sm);
    }
    fullbar(bar);
    // phase C: logits (emb from LDS) + LSE + top-2 screening
    if (blk < NVT)
      logits_block(blk, tid, hshi + ((size_t)q * 2 + 1) * HS, gr0, gr1, red, sm);
    fullbar(bar);
    // phase D: final reduce + exact rescore + sample (blocks 32..95)
    if (blk >= 32 && blk < 32 + BATCH)
      sample_block(blk - 32, tid, t, red, emb, hbuf + HS, gum_t, xhi, xlo, out, sm);
    fullbar(bar);
  }
}

}  // namespace

extern "C" void kernel_launch(void* const* d_in, const int* in_sizes, int n_in,
                              void* d_out, int out_size, void* d_ws, size_t ws_size,
                              hipStream_t stream) {
  const float* img  = (const float*)d_in[0];
  const float* W_fh = (const float*)d_in[1];
  const float* b_fh = (const float*)d_in[2];
  const float* Wc   = (const float*)d_in[3];
  const float* bc   = (const float*)d_in[4];
  const float* Wh   = (const float*)d_in[5];
  const float* bh   = (const float*)d_in[6];
  const float* W_ih = (const float*)d_in[7];
  const float* W_hh = (const float*)d_in[8];
  const float* b_l  = (const float*)d_in[9];
  const float* emb  = (const float*)d_in[10];
  const float* gum  = (const float*)d_in[11];
  float* out = (float*)d_out;

  float* w     = (float*)d_ws;
  float* femb  = w;                                    // 3136*512
  float* fmean = femb + (size_t)3136 * 512;            // 64*512
  float* hbuf  = fmean + 64 * 512;                     // 2*64*512 f32
  float* cbuf  = hbuf + 2 * 64 * 512;                  // 2*64*512 f32
  float* red   = cbuf + 2 * 64 * 512;                  // 250*64*8
  unsigned* bar = (unsigned*)(red + 250 * 64 * 8);     // 512 uints

  unsigned short* us = (unsigned short*)(bar + 512);
  unsigned short* embbf  = us;                                  // 32000*512
  unsigned short* imghi  = embbf + (size_t)VOC * EMBN;          // 3136*2048
  unsigned short* imglo  = imghi + (size_t)3136 * 2048;
  unsigned short* wfh_hi = imglo + (size_t)3136 * 2048;         // 512*2048 (W_fh^T)
  unsigned short* wfh_lo = wfh_hi + (size_t)512 * 2048;
  unsigned short* wg     = wfh_lo + (size_t)512 * 2048;         // [l][mat][hi/lo][2048][512]
  const size_t WGM = (size_t)G4 * 512;
  unsigned short* xhi    = wg + 8 * WGM;                        // 64*512
  unsigned short* xlo    = xhi + 64 * 512;
  unsigned short* hshi   = xlo + 64 * 512;                      // [2 parity][2 layer][64][512]
  unsigned short* hslo   = hshi + (size_t)4 * 64 * 512;

  auto wgp = [&](int l, int mat, int part_) -> unsigned short* {
    return wg + (((size_t)l * 2 + mat) * 2 + part_) * WGM;
  };

  // ---- one-time prep ----
  k_emb2bf<<<8000, 256, 0, stream>>>(emb, embbf);
  k_split<<<3136 * 2048 / 8 / 256, 256, 0, stream>>>(img, imghi, imglo);
  k_trans<<<dim3(FEATN / 32, FHN / 32), 256, 0, stream>>>(W_fh, wfh_hi, wfh_lo, FEATN, FHN);
  for (int l = 0; l < 2; ++l) {
    k_trans<<<dim3(EMBN / 32, G4 / 32), 256, 0, stream>>>(W_ih + (size_t)l * EMBN * G4, wgp(l, 0, 0), wgp(l, 0, 1), EMBN, G4);
    k_trans<<<dim3(HID / 32, G4 / 32), 256, 0, stream>>>(W_hh + (size_t)l * HID * G4, wgp(l, 1, 0), wgp(l, 1, 1), HID, G4);
  }
  k_feat_mfma<<<dim3(49, 8), 256, 0, stream>>>(imghi, imglo, wfh_hi, wfh_lo, b_fh, femb);
  k_mean<<<128, 256, 0, stream>>>(femb, fmean);
  k_h0c0<<<dim3(8, 2, 2), 256, 0, stream>>>(fmean, Wc, bc, Wh, bh, hbuf, cbuf, hshi, hslo);
  k_initx<<<128, 256, 0, stream>>>(xhi, xlo);
  k_zero<<<1, 512, 0, stream>>>(bar);

  // ---- persistent 40-step decode: emb pinned in LDS, gumbel pre-loaded to regs ----
  k_persist<<<NBLK, 1024, 0, stream>>>(embbf, emb, gum, wg, b_l, hbuf, cbuf,
                                       xhi, xlo, hshi, hslo, red, out, bar);
}

// Round 7
// 5935.056 us; speedup vs baseline: 2.6573x; 1.5246x over previous
//
#include <hip/hip_runtime.h>
#include <cmath>

namespace {

constexpr int BATCH = 64;
constexpr int NREG  = 49;
constexpr int FEATN = 2048;
constexpr int FHN   = 512;
constexpr int HID   = 512;
constexpr int EMBN  = 512;
constexpr int VOC   = 32000;
constexpr int TSTEPS= 40;
constexpr int G4    = 2048;       // 4*H
constexpr int NVT   = VOC / 128;  // 250 v-tiles for logits
constexpr int NBLK  = 256;        // persistent grid (1 block/CU)
constexpr int NLSTM = 128;        // blocks doing LSTM phases

typedef short bf16x8 __attribute__((ext_vector_type(8)));
typedef float f32x4  __attribute__((ext_vector_type(4)));

__device__ __forceinline__ float sigm(float x) { return 1.0f / (1.0f + expf(-x)); }

__device__ __forceinline__ unsigned short f2bf(float f) {
  unsigned u = __float_as_uint(f);
  unsigned r = (u + 0x7fffu + ((u >> 16) & 1u)) >> 16;   // RNE
  return (unsigned short)r;
}
__device__ __forceinline__ float bf2f(unsigned short h) {
  return __uint_as_float(((unsigned)h) << 16);
}

__device__ __forceinline__ bool better(float a, int ia, float b, int ib) {
  return a > b || (a == b && ia < ib);
}
__device__ __forceinline__ void top2_merge(float& v1, int& i1, float& v2, int& i2,
                                           float u1, int j1, float u2, int j2) {
  if (better(u1, j1, v1, i1)) {
    float t = v1; int ti = i1;
    v1 = u1; i1 = j1;
    if (better(u2, j2, t, ti)) { v2 = u2; i2 = j2; } else { v2 = t; i2 = ti; }
  } else {
    if (better(u1, j1, v2, i2)) { v2 = u1; i2 = j1; }
  }
}
__device__ __forceinline__ void lse_merge(float& m, float& s, float om, float os) {
  float nm = fmaxf(m, om);
  float ns = 0.f;
  if (m  > -INFINITY) ns += s  * expf(m  - nm);
  if (om > -INFINITY) ns += os * expf(om - nm);
  m = nm; s = ns;
}

// ================= shared memory: persistent emb tile + phase union =================
struct Smem {
  unsigned short embl[128 * 512];            // 128KB, XOR-swizzled rows, PERSISTENT all 40 steps
  union {
    float gs[4][64][16];                     // LSTM K-split partials [ksl][batch][row16] 16KB
    struct {                                 // phase C reduction (12KB)
      float rm[512], rs[512], rv1[512], rv2[512];
      int   ri1[512], ri2[512];
    } c;
    struct {                                 // phase D (10KB)
      float rm[256], rs[256], rv1[256], rv2[256];
      int   ri1[256], ri2[256];
      float s1[512], s2[512];
    } d;
  } u;
};                                           // 147456 B total -> 1 block/CU

// ================= barriers =================
// bar: shard counters at 32*s (s=0..7), master 288, gen 320, mini counter 352, mini gen 384
__device__ __forceinline__ void fullbar(unsigned* bar) {
  __syncthreads();
  if (threadIdx.x == 0) {
    __threadfence();
    unsigned gen = __hip_atomic_load(bar + 320, __ATOMIC_RELAXED, __HIP_MEMORY_SCOPE_AGENT);
    const int shard = blockIdx.x & 7;
    unsigned a = __hip_atomic_fetch_add(bar + shard * 32, 1u, __ATOMIC_ACQ_REL, __HIP_MEMORY_SCOPE_AGENT);
    if (a == 31u) {
      __hip_atomic_store(bar + shard * 32, 0u, __ATOMIC_RELAXED, __HIP_MEMORY_SCOPE_AGENT);
      unsigned m = __hip_atomic_fetch_add(bar + 288, 1u, __ATOMIC_ACQ_REL, __HIP_MEMORY_SCOPE_AGENT);
      if (m == 7u) {
        __hip_atomic_store(bar + 288, 0u, __ATOMIC_RELAXED, __HIP_MEMORY_SCOPE_AGENT);
        __hip_atomic_fetch_add(bar + 320, 1u, __ATOMIC_RELEASE, __HIP_MEMORY_SCOPE_AGENT);
      }
    }
    while (__hip_atomic_load(bar + 320, __ATOMIC_RELAXED, __HIP_MEMORY_SCOPE_AGENT) == gen)
      __builtin_amdgcn_s_sleep(2);
    __threadfence();
  }
  __syncthreads();
}

__device__ __forceinline__ void minibar(unsigned* bar) {   // LSTM blocks 0..127 only
  __syncthreads();
  if (threadIdx.x == 0) {
    __threadfence();
    unsigned gen = __hip_atomic_load(bar + 384, __ATOMIC_RELAXED, __HIP_MEMORY_SCOPE_AGENT);
    unsigned a = __hip_atomic_fetch_add(bar + 352, 1u, __ATOMIC_ACQ_REL, __HIP_MEMORY_SCOPE_AGENT);
    if (a == (unsigned)NLSTM - 1) {
      __hip_atomic_store(bar + 352, 0u, __ATOMIC_RELAXED, __HIP_MEMORY_SCOPE_AGENT);
      __hip_atomic_fetch_add(bar + 384, 1u, __ATOMIC_RELEASE, __HIP_MEMORY_SCOPE_AGENT);
    }
    while (__hip_atomic_load(bar + 384, __ATOMIC_RELAXED, __HIP_MEMORY_SCOPE_AGENT) == gen)
      __builtin_amdgcn_s_sleep(1);
    __threadfence();
  }
  __syncthreads();
}

// ================= prep kernels (one-time, unchanged) =================

__global__ __launch_bounds__(256) void k_trans(const float* __restrict__ src,
    unsigned short* __restrict__ dhi, unsigned short* __restrict__ dlo, int K, int N) {
  __shared__ float tile[32][33];
  const int k0 = blockIdx.x * 32, n0 = blockIdx.y * 32;
  const int tx = threadIdx.x & 31, ty = threadIdx.x >> 5;
#pragma unroll
  for (int r = ty; r < 32; r += 8) tile[r][tx] = src[(size_t)(k0 + r) * N + n0 + tx];
  __syncthreads();
#pragma unroll
  for (int r = ty; r < 32; r += 8) {
    float v = tile[tx][r];
    unsigned short hv = f2bf(v);
    size_t o = (size_t)(n0 + r) * K + k0 + tx;
    dhi[o] = hv;
    dlo[o] = f2bf(v - bf2f(hv));
  }
}

__global__ void k_split(const float* __restrict__ src, unsigned short* __restrict__ dhi,
                        unsigned short* __restrict__ dlo) {
  const size_t i = (size_t)blockIdx.x * 256 + threadIdx.x;
  const float4* p = reinterpret_cast<const float4*>(src) + i * 2;
  float4 a = p[0], b = p[1];
  float v[8] = {a.x, a.y, a.z, a.w, b.x, b.y, b.z, b.w};
  unsigned short hi[8], lo[8];
#pragma unroll
  for (int j = 0; j < 8; ++j) {
    hi[j] = f2bf(v[j]);
    lo[j] = f2bf(v[j] - bf2f(hi[j]));
  }
  uint4 oh, ol;
  oh.x = hi[0] | (hi[1] << 16); oh.y = hi[2] | (hi[3] << 16);
  oh.z = hi[4] | (hi[5] << 16); oh.w = hi[6] | (hi[7] << 16);
  ol.x = lo[0] | (lo[1] << 16); ol.y = lo[2] | (lo[3] << 16);
  ol.z = lo[4] | (lo[5] << 16); ol.w = lo[6] | (lo[7] << 16);
  reinterpret_cast<uint4*>(dhi)[i] = oh;
  reinterpret_cast<uint4*>(dlo)[i] = ol;
}

__global__ void k_emb2bf(const float* __restrict__ emb, unsigned short* __restrict__ ebf) {
  const size_t i = (size_t)blockIdx.x * 256 + threadIdx.x;
  const float4* p = reinterpret_cast<const float4*>(emb) + i * 2;
  float4 a = p[0], b = p[1];
  uint4 o;
  o.x = (unsigned)f2bf(a.x) | ((unsigned)f2bf(a.y) << 16);
  o.y = (unsigned)f2bf(a.z) | ((unsigned)f2bf(a.w) << 16);
  o.z = (unsigned)f2bf(b.x) | ((unsigned)f2bf(b.y) << 16);
  o.w = (unsigned)f2bf(b.z) | ((unsigned)f2bf(b.w) << 16);
  reinterpret_cast<uint4*>(ebf)[i] = o;
}

__global__ __launch_bounds__(256) void k_feat_mfma(
    const unsigned short* __restrict__ Ahi, const unsigned short* __restrict__ Alo,
    const unsigned short* __restrict__ Bhi, const unsigned short* __restrict__ Blo,
    const float* __restrict__ bias, float* __restrict__ femb) {
  const int m0 = blockIdx.x * 64, n0 = blockIdx.y * 64;
  const int tid = threadIdx.x, lane = tid & 63, w = tid >> 6;
  const int l15 = lane & 15, l4 = lane >> 4;
  f32x4 acc[4];
#pragma unroll
  for (int nt = 0; nt < 4; ++nt) acc[nt] = (f32x4){0.f, 0.f, 0.f, 0.f};
  const size_t arow = (size_t)(m0 + w * 16 + l15) * FEATN;
  for (int kk = 0; kk < FEATN / 32; ++kk) {
    const int k = kk * 32 + l4 * 8;
    bf16x8 a1 = *reinterpret_cast<const bf16x8*>(Ahi + arow + k);
    bf16x8 a2 = *reinterpret_cast<const bf16x8*>(Alo + arow + k);
#pragma unroll
    for (int nt = 0; nt < 4; ++nt) {
      const size_t brow = (size_t)(n0 + nt * 16 + l15) * FEATN + k;
      bf16x8 b1 = *reinterpret_cast<const bf16x8*>(Bhi + brow);
      bf16x8 b2 = *reinterpret_cast<const bf16x8*>(Blo + brow);
      acc[nt] = __builtin_amdgcn_mfma_f32_16x16x32_bf16(a1, b1, acc[nt], 0, 0, 0);
      acc[nt] = __builtin_amdgcn_mfma_f32_16x16x32_bf16(a1, b2, acc[nt], 0, 0, 0);
      acc[nt] = __builtin_amdgcn_mfma_f32_16x16x32_bf16(a2, b1, acc[nt], 0, 0, 0);
    }
  }
#pragma unroll
  for (int nt = 0; nt < 4; ++nt)
#pragma unroll
    for (int i = 0; i < 4; ++i) {
      int m = m0 + w * 16 + l4 * 4 + i, n = n0 + nt * 16 + l15;
      femb[(size_t)m * FHN + n] = tanhf(acc[nt][i] + bias[n]);
    }
}

__global__ void k_mean(const float* __restrict__ femb, float* __restrict__ fmean) {
  const int gid = blockIdx.x * 256 + threadIdx.x;  // 32768
  const int b = gid >> 9, f = gid & 511;
  float s = 0.f;
  for (int n = 0; n < NREG; ++n) s += femb[(size_t)(b * NREG + n) * FHN + f];
  fmean[gid] = s * (1.0f / NREG);
}

__global__ __launch_bounds__(256) void k_h0c0(const float* __restrict__ fmean,
    const float* __restrict__ Wc, const float* __restrict__ bc,
    const float* __restrict__ Wh, const float* __restrict__ bh,
    float* __restrict__ hbuf, float* __restrict__ cbuf,
    unsigned short* __restrict__ hshi, unsigned short* __restrict__ hslo) {
  const int n0 = blockIdx.x * 64, l = blockIdx.y, isH = blockIdx.z;
  const float* W   = (isH ? Wh : Wc) + (size_t)l * FHN * HID;
  const float* bias= (isH ? bh : bc) + l * HID;
  float* outp      = (isH ? hbuf : cbuf) + (size_t)l * BATCH * HID;
  __shared__ float As[16][68], Bs[16][68];
  const int tid = threadIdx.x, tx = tid & 15, ty = tid >> 4;
  float acc[4][4] = {};
  for (int k0 = 0; k0 < FHN; k0 += 16) {
#pragma unroll
    for (int e = 0; e < 4; ++e) { int idx = tid + e * 256, m = idx >> 4, k = idx & 15; As[k][m] = fmean[m * FHN + k0 + k]; }
#pragma unroll
    for (int e = 0; e < 4; ++e) { int idx = tid + e * 256, k = idx >> 6, n = idx & 63; Bs[k][n] = W[(size_t)(k0 + k) * HID + n0 + n]; }
    __syncthreads();
#pragma unroll
    for (int k = 0; k < 16; ++k) {
      float4 av = *(const float4*)&As[k][ty * 4];
      float4 bv = *(const float4*)&Bs[k][tx * 4];
      float a[4] = {av.x, av.y, av.z, av.w}, b[4] = {bv.x, bv.y, bv.z, bv.w};
#pragma unroll
      for (int i = 0; i < 4; ++i)
#pragma unroll
        for (int j = 0; j < 4; ++j) acc[i][j] = fmaf(a[i], b[j], acc[i][j]);
    }
    __syncthreads();
  }
#pragma unroll
  for (int i = 0; i < 4; ++i) {
    int m = ty * 4 + i, n = n0 + tx * 4;
    float vals[4];
#pragma unroll
    for (int j = 0; j < 4; ++j) vals[j] = acc[i][j] + bias[n + j];
    *(float4*)&outp[(size_t)m * HID + n] = make_float4(vals[0], vals[1], vals[2], vals[3]);
    if (isH) {
#pragma unroll
      for (int j = 0; j < 4; ++j) {
        unsigned short hv = f2bf(vals[j]);
        size_t o = (size_t)l * BATCH * HID + (size_t)m * HID + n + j;  // parity-0 slot
        hshi[o] = hv;
        hslo[o] = f2bf(vals[j] - bf2f(hv));
      }
    }
  }
}

__global__ void k_initx(unsigned short* __restrict__ xhi, unsigned short* __restrict__ xlo) {
  const int i = blockIdx.x * 256 + threadIdx.x;
  xhi[i] = 0x4040; xlo[i] = 0;      // 3.0 exact in bf16
}

__global__ void k_zero(unsigned* __restrict__ bar) {
  bar[threadIdx.x] = 0;             // 512 uints
}

// ================= persistent-kernel phase bodies =================

// ---- LSTM layer phase: 128 blocks; block owns 4 cols x 4 gates (16 weight rows);
//      wave w: mt = w>>2 (batch tile), ksl = w&3 (K=128 slice). Weights in regs.
__device__ __forceinline__ void lstm_phase(
    const bf16x8 (&wl)[2][2][4],            // [mat(x/h)][part(hi/lo)][ks] for this layer
    int blk, int tid, int mt, int ksl, int l,
    const unsigned short* __restrict__ xh, const unsigned short* __restrict__ xl,
    const unsigned short* __restrict__ hh, const unsigned short* __restrict__ hl,
    const float* __restrict__ bl_,
    float* __restrict__ hbuf, float* __restrict__ cbuf,
    unsigned short* __restrict__ ho_hi, unsigned short* __restrict__ ho_lo,
    Smem& sm) {
  const int lane = tid & 63;
  const int l15 = lane & 15, l4 = lane >> 4;
  f32x4 acc = (f32x4){0.f, 0.f, 0.f, 0.f};
  const size_t arow = (size_t)(mt * 16 + l15) * 512 + ksl * 128 + l4 * 8;
#pragma unroll
  for (int ks = 0; ks < 4; ++ks) {           // x @ Wih (3-term bf16 split)
    bf16x8 a1 = *reinterpret_cast<const bf16x8*>(xh + arow + ks * 32);
    bf16x8 a2 = *reinterpret_cast<const bf16x8*>(xl + arow + ks * 32);
    acc = __builtin_amdgcn_mfma_f32_16x16x32_bf16(a1, wl[0][0][ks], acc, 0, 0, 0);
    acc = __builtin_amdgcn_mfma_f32_16x16x32_bf16(a1, wl[0][1][ks], acc, 0, 0, 0);
    acc = __builtin_amdgcn_mfma_f32_16x16x32_bf16(a2, wl[0][0][ks], acc, 0, 0, 0);
  }
#pragma unroll
  for (int ks = 0; ks < 4; ++ks) {           // h @ Whh
    bf16x8 a1 = *reinterpret_cast<const bf16x8*>(hh + arow + ks * 32);
    bf16x8 a2 = *reinterpret_cast<const bf16x8*>(hl + arow + ks * 32);
    acc = __builtin_amdgcn_mfma_f32_16x16x32_bf16(a1, wl[1][0][ks], acc, 0, 0, 0);
    acc = __builtin_amdgcn_mfma_f32_16x16x32_bf16(a1, wl[1][1][ks], acc, 0, 0, 0);
    acc = __builtin_amdgcn_mfma_f32_16x16x32_bf16(a2, wl[1][0][ks], acc, 0, 0, 0);
  }
  // C/D layout: n = l15 (weight row), m = l4*4 + i (batch within mt)
#pragma unroll
  for (int i = 0; i < 4; ++i)
    sm.u.gs[ksl][mt * 16 + l4 * 4 + i][l15] = acc[i];
  __syncthreads();
  if (tid < 256) {                           // cell: 64 batches x 4 cols
    const int b = tid >> 2, c = tid & 3, j = blk * 4 + c;
    float g0 = 0.f, g1 = 0.f, g2 = 0.f, g3 = 0.f;
#pragma unroll
    for (int k2 = 0; k2 < 4; ++k2) {
      g0 += sm.u.gs[k2][b][c];
      g1 += sm.u.gs[k2][b][4 + c];
      g2 += sm.u.gs[k2][b][8 + c];
      g3 += sm.u.gs[k2][b][12 + c];
    }
    g0 += bl_[l * 2048 + j];
    g1 += bl_[l * 2048 + 512 + j];
    g2 += bl_[l * 2048 + 1024 + j];
    g3 += bl_[l * 2048 + 1536 + j];
    const size_t o = (size_t)l * BATCH * HID + (size_t)b * HID + j;
    float cn = sigm(g1) * cbuf[o] + sigm(g0) * tanhf(g2);
    float hn = sigm(g3) * tanhf(cn);
    cbuf[o] = cn; hbuf[o] = hn;
    unsigned short hv = f2bf(hn);
    ho_hi[b * HID + j] = hv; ho_lo[b * HID + j] = f2bf(hn - bf2f(hv));
  }
  __syncthreads();
}

// ---- logits tile: A-frags from persistent LDS emb tile; gumbel pre-loaded regs ----
__device__ __forceinline__ void logits_block(int blk, int tid,
    const unsigned short* __restrict__ h1hi, const float4 gr0, const float4 gr1,
    float* __restrict__ red, Smem& sm) {
  const int v0 = blk * 128;
  const int lane = tid & 63, w = tid >> 6;
  const int l15 = lane & 15, l4 = lane >> 4;
  const int vsub = w >> 1, bhalf = w & 1;
  const int arow = vsub * 16 + l15;
  const char* abase = reinterpret_cast<const char*>(sm.embl) + arow * 1024;
  const int axor = (arow & 7) << 4;

  f32x4 acc[2];
  acc[0] = (f32x4){0.f, 0.f, 0.f, 0.f};
  acc[1] = (f32x4){0.f, 0.f, 0.f, 0.f};
#pragma unroll
  for (int ks = 0; ks < 16; ++ks) {
    bf16x8 a0 = *reinterpret_cast<const bf16x8*>(abase + ((ks * 64 + l4 * 16) ^ axor));
#pragma unroll
    for (int nl = 0; nl < 2; ++nl) {
      const int brow = (bhalf * 2 + nl) * 16 + l15;
      bf16x8 bb = *reinterpret_cast<const bf16x8*>(h1hi + (size_t)brow * 512 + ks * 32 + l4 * 8);
      acc[nl] = __builtin_amdgcn_mfma_f32_16x16x32_bf16(a0, bb, acc[nl], 0, 0, 0);
    }
  }

  const int vb = v0 + vsub * 16 + l4 * 4;
#pragma unroll
  for (int nl = 0; nl < 2; ++nl) {
    const float4 g0 = nl ? gr1 : gr0;
    float lg[4] = {acc[nl][0], acc[nl][1], acc[nl][2], acc[nl][3]};
    float gv[4] = {g0.x, g0.y, g0.z, g0.w};
    float mx = fmaxf(fmaxf(lg[0], lg[1]), fmaxf(lg[2], lg[3]));
    float ss = 0.f;
    float v1 = -INFINITY, v2 = -INFINITY; int i1 = 0x7fffffff, i2 = 0x7fffffff;
#pragma unroll
    for (int i = 0; i < 4; ++i) {
      ss += expf(lg[i] - mx);
      float val = lg[i] + gv[i];
      int idx = vb + i;
      if (better(val, idx, v1, i1)) { v2 = v1; i2 = i1; v1 = val; i1 = idx; }
      else if (better(val, idx, v2, i2)) { v2 = val; i2 = idx; }
    }
#pragma unroll
    for (int mask = 16; mask <= 32; mask <<= 1) {
      float om = __shfl_xor(mx, mask);
      float os = __shfl_xor(ss, mask);
      float u1 = __shfl_xor(v1, mask); int j1 = __shfl_xor(i1, mask);
      float u2 = __shfl_xor(v2, mask); int j2 = __shfl_xor(i2, mask);
      lse_merge(mx, ss, om, os);
      top2_merge(v1, i1, v2, i2, u1, j1, u2, j2);
    }
    if (lane < 16) {
      int slot = (w * 2 + nl) * 16 + l15;
      sm.u.c.rm[slot] = mx; sm.u.c.rs[slot] = ss;
      sm.u.c.rv1[slot] = v1; sm.u.c.ri1[slot] = i1; sm.u.c.rv2[slot] = v2; sm.u.c.ri2[slot] = i2;
    }
  }
  __syncthreads();
  if (tid < 64) {
    const int b = tid, bh = b >> 5, nl = (b >> 4) & 1, c = b & 15;
    int s0 = (bh * 2 + nl) * 16 + c;             // vsub = 0
    float M = sm.u.c.rm[s0], S = sm.u.c.rs[s0], V1 = sm.u.c.rv1[s0], V2 = sm.u.c.rv2[s0];
    int I1 = sm.u.c.ri1[s0], I2 = sm.u.c.ri2[s0];
#pragma unroll
    for (int vs = 1; vs < 8; ++vs) {
      int sl = ((vs * 2 + bh) * 2 + nl) * 16 + c;
      lse_merge(M, S, sm.u.c.rm[sl], sm.u.c.rs[sl]);
      top2_merge(V1, I1, V2, I2, sm.u.c.rv1[sl], sm.u.c.ri1[sl], sm.u.c.rv2[sl], sm.u.c.ri2[sl]);
    }
    float* rp = red + ((size_t)blk * 64 + tid) * 8;
    rp[0] = M; rp[1] = S;
    rp[2] = V1; rp[3] = __int_as_float(I1);
    rp[4] = V2; rp[5] = __int_as_float(I2);
  }
}

// ---- final reduce + exact f32 rescore + sample ----
__device__ __forceinline__ void sample_block(int b, int tid, int t,
    const float* __restrict__ red, const float* __restrict__ emb,
    const float* __restrict__ h1f, const float* __restrict__ gum_t,
    unsigned short* __restrict__ xhi, unsigned short* __restrict__ xlo,
    float* __restrict__ out, Smem& sm) {
  if (tid < 256) {
    float m = -INFINITY, s = 0.f, v1 = -INFINITY, v2 = -INFINITY;
    int i1 = 0x7fffffff, i2 = 0x7fffffff;
    if (tid < NVT) {
      const float* rp = red + ((size_t)tid * 64 + b) * 8;
      m = rp[0]; s = rp[1];
      v1 = rp[2]; i1 = __float_as_int(rp[3]);
      v2 = rp[4]; i2 = __float_as_int(rp[5]);
    }
    sm.u.d.rm[tid] = m; sm.u.d.rs[tid] = s;
    sm.u.d.rv1[tid] = v1; sm.u.d.ri1[tid] = i1; sm.u.d.rv2[tid] = v2; sm.u.d.ri2[tid] = i2;
  }
  __syncthreads();
  for (int off = 128; off > 0; off >>= 1) {
    if (tid < off) {
      float M = sm.u.d.rm[tid], S = sm.u.d.rs[tid];
      lse_merge(M, S, sm.u.d.rm[tid + off], sm.u.d.rs[tid + off]);
      sm.u.d.rm[tid] = M; sm.u.d.rs[tid] = S;
      float a1 = sm.u.d.rv1[tid], a2 = sm.u.d.rv2[tid]; int c1 = sm.u.d.ri1[tid], c2 = sm.u.d.ri2[tid];
      top2_merge(a1, c1, a2, c2, sm.u.d.rv1[tid + off], sm.u.d.ri1[tid + off],
                 sm.u.d.rv2[tid + off], sm.u.d.ri2[tid + off]);
      sm.u.d.rv1[tid] = a1; sm.u.d.ri1[tid] = c1; sm.u.d.rv2[tid] = a2; sm.u.d.ri2[tid] = c2;
    }
    __syncthreads();
  }
  const int I1 = sm.u.d.ri1[0], I2 = sm.u.d.ri2[0];
  const float lse = sm.u.d.rm[0] + logf(sm.u.d.rs[0]);
  const float* e1 = emb + (size_t)I1 * EMBN;
  const float* e2 = emb + (size_t)I2 * EMBN;
  const float* hb = h1f + b * EMBN;
  if (tid < 512) {
    float hv = hb[tid];
    sm.u.d.s1[tid] = e1[tid] * hv;
    sm.u.d.s2[tid] = e2[tid] * hv;
  }
  __syncthreads();
  for (int off = 256; off > 0; off >>= 1) {
    if (tid < off) { sm.u.d.s1[tid] += sm.u.d.s1[tid + off]; sm.u.d.s2[tid] += sm.u.d.s2[tid + off]; }
    __syncthreads();
  }
  const float d1 = sm.u.d.s1[0], d2 = sm.u.d.s2[0];
  const float x1 = d1 + gum_t[(size_t)b * VOC + I1];
  const float x2 = d2 + gum_t[(size_t)b * VOC + I2];
  int tok; float dsel;
  if (x2 > x1 || (x2 == x1 && I2 < I1)) { tok = I2; dsel = d2; }
  else                                  { tok = I1; dsel = d1; }
  if (tid < 512) {
    float ev = emb[(size_t)tok * EMBN + tid];
    unsigned short hv = f2bf(ev);
    xhi[b * EMBN + tid] = hv;
    xlo[b * EMBN + tid] = f2bf(ev - bf2f(hv));
  }
  if (tid == 0) {
    out[b * TSTEPS + t] = (float)tok;
    out[BATCH * TSTEPS + b * TSTEPS + t] = dsel - lse;
  }
}

// ================= persistent decode kernel: 256 blocks x 1024 threads =================
__global__ __launch_bounds__(1024, 4) void k_persist(
    const unsigned short* __restrict__ embbf, const float* __restrict__ emb,
    const float* __restrict__ gum, const unsigned short* __restrict__ wg,
    const float* __restrict__ b_l, float* __restrict__ hbuf, float* __restrict__ cbuf,
    unsigned short* __restrict__ xhi, unsigned short* __restrict__ xlo,
    unsigned short* __restrict__ hshi, unsigned short* __restrict__ hslo,
    float* __restrict__ red, float* __restrict__ out, unsigned* __restrict__ bar) {
  __shared__ Smem sm;
  const int blk = blockIdx.x, tid = threadIdx.x;
  const size_t HS = (size_t)BATCH * HID;   // per (parity,layer) slot
  const int lane = tid & 63, w = tid >> 6;
  const int l15 = lane & 15, l4 = lane >> 4;
  const int mt = w >> 2, ksl = w & 3;      // LSTM wave roles
  const size_t WGM = (size_t)G4 * 512;

  // ---- one-time: pin this block's LSTM weight slice in registers ----
  // block owns 16 weight rows: row(g,c) = g*512 + blk*4 + c ; lane l15 -> (g=l15>>2, c=l15&3)
  // wave's K slice: [ksl*128, ksl*128+128) ; wr[layer][mat][part][ks] (static idx only)
  bf16x8 wr[2][2][2][4];
  if (blk < NLSTM) {
    const int wrow = (l15 >> 2) * 512 + blk * 4 + (l15 & 3);
#pragma unroll
    for (int l = 0; l < 2; ++l)
#pragma unroll
      for (int m = 0; m < 2; ++m)
#pragma unroll
        for (int p = 0; p < 2; ++p) {
          const unsigned short* base = wg + (((size_t)l * 2 + m) * 2 + p) * WGM
                                          + (size_t)wrow * 512 + ksl * 128 + l4 * 8;
#pragma unroll
          for (int ks = 0; ks < 4; ++ks)
            wr[l][m][p][ks] = *reinterpret_cast<const bf16x8*>(base + ks * 32);
        }
  }

  // ---- one-time: stage this block's emb v-tile into LDS (persistent, XOR-swizzled) ----
  if (blk < NVT) {
    const uint4* ep = reinterpret_cast<const uint4*>(embbf + (size_t)blk * 128 * 512);
#pragma unroll
    for (int i = 0; i < 8; ++i) {
      int c = tid + i * 1024;              // 16B chunk, 8192 total (64 per row)
      int row = c >> 6;
      int inb = (c & 63) << 4;
      uint4 v = ep[c];
      int sw = inb ^ ((row & 7) << 4);
      *reinterpret_cast<uint4*>(reinterpret_cast<char*>(sm.embl) + row * 1024 + sw) = v;
    }
  }
  __syncthreads();

  for (int t = 0; t < TSTEPS; ++t) {
    const float* gum_t = gum + (size_t)t * BATCH * VOC;
    const int p = t & 1, q = p ^ 1;

    // pre-load this thread's phase-C gumbel values -> in flight across LSTM + barrier
    float4 gr0 = make_float4(0.f, 0.f, 0.f, 0.f), gr1 = gr0;
    if (blk < NVT) {
      const int vb_ = blk * 128 + (w >> 1) * 16 + l4 * 4;
      const int b0 = ((w & 1) * 2 + 0) * 16 + l15;
      const int b1 = ((w & 1) * 2 + 1) * 16 + l15;
      gr0 = *reinterpret_cast<const float4*>(gum_t + (size_t)b0 * VOC + vb_);
      gr1 = *reinterpret_cast<const float4*>(gum_t + (size_t)b1 * VOC + vb_);
    }

    if (blk < NLSTM) {
      // phase A: layer 0 (x, h0[p] -> h0[q])
      lstm_phase(wr[0], blk, tid, mt, ksl, 0, xhi, xlo,
                 hshi + ((size_t)p * 2 + 0) * HS, hslo + ((size_t)p * 2 + 0) * HS,
                 b_l, hbuf, cbuf,
                 hshi + ((size_t)q * 2 + 0) * HS, hslo + ((size_t)q * 2 + 0) * HS, sm);
      minibar(bar);
      // phase B: layer 1 (h0[q], h1[p] -> h1[q])
      lstm_phase(wr[1], blk, tid, mt, ksl, 1,
                 hshi + ((size_t)q * 2 + 0) * HS, hslo + ((size_t)q * 2 + 0) * HS,
                 hshi + ((size_t)p * 2 + 1) * HS, hslo + ((size_t)p * 2 + 1) * HS,
                 b_l, hbuf, cbuf,
                 hshi + ((size_t)q * 2 + 1) * HS, hslo + ((size_t)q * 2 + 1) * HS, sm);
    }
    fullbar(bar);
    // phase C: logits (emb from LDS) + LSE + top-2 screening
    if (blk < NVT)
      logits_block(blk, tid, hshi + ((size_t)q * 2 + 1) * HS, gr0, gr1, red, sm);
    fullbar(bar);
    // phase D: final reduce + exact rescore + sample (blocks 128..191)
    if (blk >= NLSTM && blk < NLSTM + BATCH)
      sample_block(blk - NLSTM, tid, t, red, emb, hbuf + HS, gum_t, xhi, xlo, out, sm);
    fullbar(bar);
  }
}

}  // namespace

extern "C" void kernel_launch(void* const* d_in, const int* in_sizes, int n_in,
                              void* d_out, int out_size, void* d_ws, size_t ws_size,
                              hipStream_t stream) {
  const float* img  = (const float*)d_in[0];
  const float* W_fh = (const float*)d_in[1];
  const float* b_fh = (const float*)d_in[2];
  const float* Wc   = (const float*)d_in[3];
  const float* bc   = (const float*)d_in[4];
  const float* Wh   = (const float*)d_in[5];
  const float* bh   = (const float*)d_in[6];
  const float* W_ih = (const float*)d_in[7];
  const float* W_hh = (const float*)d_in[8];
  const float* b_l  = (const float*)d_in[9];
  const float* emb  = (const float*)d_in[10];
  const float* gum  = (const float*)d_in[11];
  float* out = (float*)d_out;

  float* w     = (float*)d_ws;
  float* femb  = w;                                    // 3136*512
  float* fmean = femb + (size_t)3136 * 512;            // 64*512
  float* hbuf  = fmean + 64 * 512;                     // 2*64*512 f32
  float* cbuf  = hbuf + 2 * 64 * 512;                  // 2*64*512 f32
  float* red   = cbuf + 2 * 64 * 512;                  // 250*64*8
  unsigned* bar = (unsigned*)(red + 250 * 64 * 8);     // 512 uints

  unsigned short* us = (unsigned short*)(bar + 512);
  unsigned short* embbf  = us;                                  // 32000*512
  unsigned short* imghi  = embbf + (size_t)VOC * EMBN;          // 3136*2048
  unsigned short* imglo  = imghi + (size_t)3136 * 2048;
  unsigned short* wfh_hi = imglo + (size_t)3136 * 2048;         // 512*2048 (W_fh^T)
  unsigned short* wfh_lo = wfh_hi + (size_t)512 * 2048;
  unsigned short* wg     = wfh_lo + (size_t)512 * 2048;         // [l][mat][hi/lo][2048][512]
  const size_t WGM = (size_t)G4 * 512;
  unsigned short* xhi    = wg + 8 * WGM;                        // 64*512
  unsigned short* xlo    = xhi + 64 * 512;
  unsigned short* hshi   = xlo + 64 * 512;                      // [2 parity][2 layer][64][512]
  unsigned short* hslo   = hshi + (size_t)4 * 64 * 512;

  auto wgp = [&](int l, int mat, int part_) -> unsigned short* {
    return wg + (((size_t)l * 2 + mat) * 2 + part_) * WGM;
  };

  // ---- one-time prep ----
  k_emb2bf<<<8000, 256, 0, stream>>>(emb, embbf);
  k_split<<<3136 * 2048 / 8 / 256, 256, 0, stream>>>(img, imghi, imglo);
  k_trans<<<dim3(FEATN / 32, FHN / 32), 256, 0, stream>>>(W_fh, wfh_hi, wfh_lo, FEATN, FHN);
  for (int l = 0; l < 2; ++l) {
    k_trans<<<dim3(EMBN / 32, G4 / 32), 256, 0, stream>>>(W_ih + (size_t)l * EMBN * G4, wgp(l, 0, 0), wgp(l, 0, 1), EMBN, G4);
    k_trans<<<dim3(HID / 32, G4 / 32), 256, 0, stream>>>(W_hh + (size_t)l * HID * G4, wgp(l, 1, 0), wgp(l, 1, 1), HID, G4);
  }
  k_feat_mfma<<<dim3(49, 8), 256, 0, stream>>>(imghi, imglo, wfh_hi, wfh_lo, b_fh, femb);
  k_mean<<<128, 256, 0, stream>>>(femb, fmean);
  k_h0c0<<<dim3(8, 2, 2), 256, 0, stream>>>(fmean, Wc, bc, Wh, bh, hbuf, cbuf, hshi, hslo);
  k_initx<<<128, 256, 0, stream>>>(xhi, xlo);
  k_zero<<<1, 512, 0, stream>>>(bar);

  // ---- persistent decode: emb pinned in LDS, LSTM weights pinned in VGPRs ----
  k_persist<<<NBLK, 1024, 0, stream>>>(embbf, emb, gum, wg, b_l, hbuf, cbuf,
                                       xhi, xlo, hshi, hslo, red, out, bar);
}

// Round 8
// 5277.760 us; speedup vs baseline: 2.9882x; 1.1245x over previous
//
#include <hip/hip_runtime.h>
#include <cmath>

namespace {

constexpr int BATCH = 64;
constexpr int NREG  = 49;
constexpr int FEATN = 2048;
constexpr int FHN   = 512;
constexpr int HID   = 512;
constexpr int EMBN  = 512;
constexpr int VOC   = 32000;
constexpr int TSTEPS= 40;
constexpr int G4    = 2048;       // 4*H
constexpr int NVT   = VOC / 128;  // 250 v-tiles for logits
constexpr int NBLK  = 256;        // persistent grid (1 block/CU)
constexpr int NLSTM = 128;        // blocks doing LSTM phases
constexpr int NTHR  = 512;        // 8 waves/block -> VGPR budget 256

typedef short bf16x8 __attribute__((ext_vector_type(8)));
typedef float f32x4  __attribute__((ext_vector_type(4)));

__device__ __forceinline__ float sigm(float x) { return 1.0f / (1.0f + expf(-x)); }

__device__ __forceinline__ unsigned short f2bf(float f) {
  unsigned u = __float_as_uint(f);
  unsigned r = (u + 0x7fffu + ((u >> 16) & 1u)) >> 16;   // RNE
  return (unsigned short)r;
}
__device__ __forceinline__ float bf2f(unsigned short h) {
  return __uint_as_float(((unsigned)h) << 16);
}
// anti-rematerialization: value becomes asm-produced; compiler must keep it live
__device__ __forceinline__ void pin(bf16x8& v) { asm volatile("" : "+v"(v)); }

__device__ __forceinline__ bool better(float a, int ia, float b, int ib) {
  return a > b || (a == b && ia < ib);
}
__device__ __forceinline__ void top2_merge(float& v1, int& i1, float& v2, int& i2,
                                           float u1, int j1, float u2, int j2) {
  if (better(u1, j1, v1, i1)) {
    float t = v1; int ti = i1;
    v1 = u1; i1 = j1;
    if (better(u2, j2, t, ti)) { v2 = u2; i2 = j2; } else { v2 = t; i2 = ti; }
  } else {
    if (better(u1, j1, v2, i2)) { v2 = u1; i2 = j1; }
  }
}
__device__ __forceinline__ void lse_merge(float& m, float& s, float om, float os) {
  float nm = fmaxf(m, om);
  float ns = 0.f;
  if (m  > -INFINITY) ns += s  * expf(m  - nm);
  if (om > -INFINITY) ns += os * expf(om - nm);
  m = nm; s = ns;
}

// ================= shared memory: persistent emb tile + phase union =================
struct Smem {
  unsigned short embl[128 * 512];            // 128KB, XOR-swizzled, PERSISTENT all 40 steps
  union {
    float gs[4][64][16];                     // LSTM K-split partials [ksl][batch][row16] 16KB
    struct {                                 // phase C reduction (12KB)
      float rm[512], rs[512], rv1[512], rv2[512];
      int   ri1[512], ri2[512];
    } c;
    struct {                                 // phase D (10KB)
      float rm[256], rs[256], rv1[256], rv2[256];
      int   ri1[256], ri2[256];
      float s1[512], s2[512];
    } d;
  } u;
};                                           // 147456 B -> 1 block/CU

// ================= barriers =================
__device__ __forceinline__ void fullbar(unsigned* bar) {
  __syncthreads();
  if (threadIdx.x == 0) {
    __threadfence();
    unsigned gen = __hip_atomic_load(bar + 320, __ATOMIC_RELAXED, __HIP_MEMORY_SCOPE_AGENT);
    const int shard = blockIdx.x & 7;
    unsigned a = __hip_atomic_fetch_add(bar + shard * 32, 1u, __ATOMIC_ACQ_REL, __HIP_MEMORY_SCOPE_AGENT);
    if (a == 31u) {
      __hip_atomic_store(bar + shard * 32, 0u, __ATOMIC_RELAXED, __HIP_MEMORY_SCOPE_AGENT);
      unsigned m = __hip_atomic_fetch_add(bar + 288, 1u, __ATOMIC_ACQ_REL, __HIP_MEMORY_SCOPE_AGENT);
      if (m == 7u) {
        __hip_atomic_store(bar + 288, 0u, __ATOMIC_RELAXED, __HIP_MEMORY_SCOPE_AGENT);
        __hip_atomic_fetch_add(bar + 320, 1u, __ATOMIC_RELEASE, __HIP_MEMORY_SCOPE_AGENT);
      }
    }
    while (__hip_atomic_load(bar + 320, __ATOMIC_RELAXED, __HIP_MEMORY_SCOPE_AGENT) == gen)
      __builtin_amdgcn_s_sleep(2);
    __threadfence();
  }
  __syncthreads();
}

__device__ __forceinline__ void minibar(unsigned* bar) {   // LSTM blocks 0..127 only
  __syncthreads();
  if (threadIdx.x == 0) {
    __threadfence();
    unsigned gen = __hip_atomic_load(bar + 384, __ATOMIC_RELAXED, __HIP_MEMORY_SCOPE_AGENT);
    unsigned a = __hip_atomic_fetch_add(bar + 352, 1u, __ATOMIC_ACQ_REL, __HIP_MEMORY_SCOPE_AGENT);
    if (a == (unsigned)NLSTM - 1) {
      __hip_atomic_store(bar + 352, 0u, __ATOMIC_RELAXED, __HIP_MEMORY_SCOPE_AGENT);
      __hip_atomic_fetch_add(bar + 384, 1u, __ATOMIC_RELEASE, __HIP_MEMORY_SCOPE_AGENT);
    }
    while (__hip_atomic_load(bar + 384, __ATOMIC_RELAXED, __HIP_MEMORY_SCOPE_AGENT) == gen)
      __builtin_amdgcn_s_sleep(1);
    __threadfence();
  }
  __syncthreads();
}

// ================= prep kernels (one-time, unchanged) =================

__global__ __launch_bounds__(256) void k_trans(const float* __restrict__ src,
    unsigned short* __restrict__ dhi, unsigned short* __restrict__ dlo, int K, int N) {
  __shared__ float tile[32][33];
  const int k0 = blockIdx.x * 32, n0 = blockIdx.y * 32;
  const int tx = threadIdx.x & 31, ty = threadIdx.x >> 5;
#pragma unroll
  for (int r = ty; r < 32; r += 8) tile[r][tx] = src[(size_t)(k0 + r) * N + n0 + tx];
  __syncthreads();
#pragma unroll
  for (int r = ty; r < 32; r += 8) {
    float v = tile[tx][r];
    unsigned short hv = f2bf(v);
    size_t o = (size_t)(n0 + r) * K + k0 + tx;
    dhi[o] = hv;
    dlo[o] = f2bf(v - bf2f(hv));
  }
}

__global__ void k_split(const float* __restrict__ src, unsigned short* __restrict__ dhi,
                        unsigned short* __restrict__ dlo) {
  const size_t i = (size_t)blockIdx.x * 256 + threadIdx.x;
  const float4* p = reinterpret_cast<const float4*>(src) + i * 2;
  float4 a = p[0], b = p[1];
  float v[8] = {a.x, a.y, a.z, a.w, b.x, b.y, b.z, b.w};
  unsigned short hi[8], lo[8];
#pragma unroll
  for (int j = 0; j < 8; ++j) {
    hi[j] = f2bf(v[j]);
    lo[j] = f2bf(v[j] - bf2f(hi[j]));
  }
  uint4 oh, ol;
  oh.x = hi[0] | (hi[1] << 16); oh.y = hi[2] | (hi[3] << 16);
  oh.z = hi[4] | (hi[5] << 16); oh.w = hi[6] | (hi[7] << 16);
  ol.x = lo[0] | (lo[1] << 16); ol.y = lo[2] | (lo[3] << 16);
  ol.z = lo[4] | (lo[5] << 16); ol.w = lo[6] | (lo[7] << 16);
  reinterpret_cast<uint4*>(dhi)[i] = oh;
  reinterpret_cast<uint4*>(dlo)[i] = ol;
}

__global__ void k_emb2bf(const float* __restrict__ emb, unsigned short* __restrict__ ebf) {
  const size_t i = (size_t)blockIdx.x * 256 + threadIdx.x;
  const float4* p = reinterpret_cast<const float4*>(emb) + i * 2;
  float4 a = p[0], b = p[1];
  uint4 o;
  o.x = (unsigned)f2bf(a.x) | ((unsigned)f2bf(a.y) << 16);
  o.y = (unsigned)f2bf(a.z) | ((unsigned)f2bf(a.w) << 16);
  o.z = (unsigned)f2bf(b.x) | ((unsigned)f2bf(b.y) << 16);
  o.w = (unsigned)f2bf(b.z) | ((unsigned)f2bf(b.w) << 16);
  reinterpret_cast<uint4*>(ebf)[i] = o;
}

__global__ __launch_bounds__(256) void k_feat_mfma(
    const unsigned short* __restrict__ Ahi, const unsigned short* __restrict__ Alo,
    const unsigned short* __restrict__ Bhi, const unsigned short* __restrict__ Blo,
    const float* __restrict__ bias, float* __restrict__ femb) {
  const int m0 = blockIdx.x * 64, n0 = blockIdx.y * 64;
  const int tid = threadIdx.x, lane = tid & 63, w = tid >> 6;
  const int l15 = lane & 15, l4 = lane >> 4;
  f32x4 acc[4];
#pragma unroll
  for (int nt = 0; nt < 4; ++nt) acc[nt] = (f32x4){0.f, 0.f, 0.f, 0.f};
  const size_t arow = (size_t)(m0 + w * 16 + l15) * FEATN;
  for (int kk = 0; kk < FEATN / 32; ++kk) {
    const int k = kk * 32 + l4 * 8;
    bf16x8 a1 = *reinterpret_cast<const bf16x8*>(Ahi + arow + k);
    bf16x8 a2 = *reinterpret_cast<const bf16x8*>(Alo + arow + k);
#pragma unroll
    for (int nt = 0; nt < 4; ++nt) {
      const size_t brow = (size_t)(n0 + nt * 16 + l15) * FEATN + k;
      bf16x8 b1 = *reinterpret_cast<const bf16x8*>(Bhi + brow);
      bf16x8 b2 = *reinterpret_cast<const bf16x8*>(Blo + brow);
      acc[nt] = __builtin_amdgcn_mfma_f32_16x16x32_bf16(a1, b1, acc[nt], 0, 0, 0);
      acc[nt] = __builtin_amdgcn_mfma_f32_16x16x32_bf16(a1, b2, acc[nt], 0, 0, 0);
      acc[nt] = __builtin_amdgcn_mfma_f32_16x16x32_bf16(a2, b1, acc[nt], 0, 0, 0);
    }
  }
#pragma unroll
  for (int nt = 0; nt < 4; ++nt)
#pragma unroll
    for (int i = 0; i < 4; ++i) {
      int m = m0 + w * 16 + l4 * 4 + i, n = n0 + nt * 16 + l15;
      femb[(size_t)m * FHN + n] = tanhf(acc[nt][i] + bias[n]);
    }
}

__global__ void k_mean(const float* __restrict__ femb, float* __restrict__ fmean) {
  const int gid = blockIdx.x * 256 + threadIdx.x;  // 32768
  const int b = gid >> 9, f = gid & 511;
  float s = 0.f;
  for (int n = 0; n < NREG; ++n) s += femb[(size_t)(b * NREG + n) * FHN + f];
  fmean[gid] = s * (1.0f / NREG);
}

__global__ __launch_bounds__(256) void k_h0c0(const float* __restrict__ fmean,
    const float* __restrict__ Wc, const float* __restrict__ bc,
    const float* __restrict__ Wh, const float* __restrict__ bh,
    float* __restrict__ hbuf, float* __restrict__ cbuf,
    unsigned short* __restrict__ hshi, unsigned short* __restrict__ hslo) {
  const int n0 = blockIdx.x * 64, l = blockIdx.y, isH = blockIdx.z;
  const float* W   = (isH ? Wh : Wc) + (size_t)l * FHN * HID;
  const float* bias= (isH ? bh : bc) + l * HID;
  float* outp      = (isH ? hbuf : cbuf) + (size_t)l * BATCH * HID;
  __shared__ float As[16][68], Bs[16][68];
  const int tid = threadIdx.x, tx = tid & 15, ty = tid >> 4;
  float acc[4][4] = {};
  for (int k0 = 0; k0 < FHN; k0 += 16) {
#pragma unroll
    for (int e = 0; e < 4; ++e) { int idx = tid + e * 256, m = idx >> 4, k = idx & 15; As[k][m] = fmean[m * FHN + k0 + k]; }
#pragma unroll
    for (int e = 0; e < 4; ++e) { int idx = tid + e * 256, k = idx >> 6, n = idx & 63; Bs[k][n] = W[(size_t)(k0 + k) * HID + n0 + n]; }
    __syncthreads();
#pragma unroll
    for (int k = 0; k < 16; ++k) {
      float4 av = *(const float4*)&As[k][ty * 4];
      float4 bv = *(const float4*)&Bs[k][tx * 4];
      float a[4] = {av.x, av.y, av.z, av.w}, b[4] = {bv.x, bv.y, bv.z, bv.w};
#pragma unroll
      for (int i = 0; i < 4; ++i)
#pragma unroll
        for (int j = 0; j < 4; ++j) acc[i][j] = fmaf(a[i], b[j], acc[i][j]);
    }
    __syncthreads();
  }
#pragma unroll
  for (int i = 0; i < 4; ++i) {
    int m = ty * 4 + i, n = n0 + tx * 4;
    float vals[4];
#pragma unroll
    for (int j = 0; j < 4; ++j) vals[j] = acc[i][j] + bias[n + j];
    *(float4*)&outp[(size_t)m * HID + n] = make_float4(vals[0], vals[1], vals[2], vals[3]);
    if (isH) {
#pragma unroll
      for (int j = 0; j < 4; ++j) {
        unsigned short hv = f2bf(vals[j]);
        size_t o = (size_t)l * BATCH * HID + (size_t)m * HID + n + j;  // parity-0 slot
        hshi[o] = hv;
        hslo[o] = f2bf(vals[j] - bf2f(hv));
      }
    }
  }
}

__global__ void k_initx(unsigned short* __restrict__ xhi, unsigned short* __restrict__ xlo) {
  const int i = blockIdx.x * 256 + threadIdx.x;
  xhi[i] = 0x4040; xlo[i] = 0;      // 3.0 exact in bf16
}

__global__ void k_zero(unsigned* __restrict__ bar) {
  bar[threadIdx.x] = 0;             // 512 uints
}

// ================= persistent-kernel phase bodies =================

// ---- LSTM layer: 128 blocks x 8 waves; wave (half=w>>2, ksl=w&3); weights in regs,
//      each wave processes batch tiles mt = half*2 and half*2+1 with its one K slice.
__device__ __forceinline__ void lstm_phase(
    const bf16x8 (&wl)[2][2][4],            // [mat(x/h)][part(hi/lo)][ks] for this layer
    int blk, int tid, int half, int ksl, int l,
    const unsigned short* __restrict__ xh, const unsigned short* __restrict__ xl,
    const unsigned short* __restrict__ hh, const unsigned short* __restrict__ hl,
    const float* __restrict__ bl_,
    float* __restrict__ hbuf, float* __restrict__ cbuf,
    unsigned short* __restrict__ ho_hi, unsigned short* __restrict__ ho_lo,
    Smem& sm) {
  const int lane = tid & 63;
  const int l15 = lane & 15, l4 = lane >> 4;
  f32x4 acc0 = (f32x4){0.f, 0.f, 0.f, 0.f};
  f32x4 acc1 = (f32x4){0.f, 0.f, 0.f, 0.f};
  const size_t ar0 = (size_t)(half * 32 + l15) * 512 + ksl * 128 + l4 * 8;
  const size_t ar1 = ar0 + 16 * 512;
#pragma unroll
  for (int ks = 0; ks < 4; ++ks) {           // x @ Wih (3-term bf16 split)
    bf16x8 a1 = *reinterpret_cast<const bf16x8*>(xh + ar0 + ks * 32);
    bf16x8 a2 = *reinterpret_cast<const bf16x8*>(xl + ar0 + ks * 32);
    acc0 = __builtin_amdgcn_mfma_f32_16x16x32_bf16(a1, wl[0][0][ks], acc0, 0, 0, 0);
    acc0 = __builtin_amdgcn_mfma_f32_16x16x32_bf16(a1, wl[0][1][ks], acc0, 0, 0, 0);
    acc0 = __builtin_amdgcn_mfma_f32_16x16x32_bf16(a2, wl[0][0][ks], acc0, 0, 0, 0);
    bf16x8 c1 = *reinterpret_cast<const bf16x8*>(xh + ar1 + ks * 32);
    bf16x8 c2 = *reinterpret_cast<const bf16x8*>(xl + ar1 + ks * 32);
    acc1 = __builtin_amdgcn_mfma_f32_16x16x32_bf16(c1, wl[0][0][ks], acc1, 0, 0, 0);
    acc1 = __builtin_amdgcn_mfma_f32_16x16x32_bf16(c1, wl[0][1][ks], acc1, 0, 0, 0);
    acc1 = __builtin_amdgcn_mfma_f32_16x16x32_bf16(c2, wl[0][0][ks], acc1, 0, 0, 0);
  }
#pragma unroll
  for (int ks = 0; ks < 4; ++ks) {           // h @ Whh
    bf16x8 a1 = *reinterpret_cast<const bf16x8*>(hh + ar0 + ks * 32);
    bf16x8 a2 = *reinterpret_cast<const bf16x8*>(hl + ar0 + ks * 32);
    acc0 = __builtin_amdgcn_mfma_f32_16x16x32_bf16(a1, wl[1][0][ks], acc0, 0, 0, 0);
    acc0 = __builtin_amdgcn_mfma_f32_16x16x32_bf16(a1, wl[1][1][ks], acc0, 0, 0, 0);
    acc0 = __builtin_amdgcn_mfma_f32_16x16x32_bf16(a2, wl[1][0][ks], acc0, 0, 0, 0);
    bf16x8 c1 = *reinterpret_cast<const bf16x8*>(hh + ar1 + ks * 32);
    bf16x8 c2 = *reinterpret_cast<const bf16x8*>(hl + ar1 + ks * 32);
    acc1 = __builtin_amdgcn_mfma_f32_16x16x32_bf16(c1, wl[1][0][ks], acc1, 0, 0, 0);
    acc1 = __builtin_amdgcn_mfma_f32_16x16x32_bf16(c1, wl[1][1][ks], acc1, 0, 0, 0);
    acc1 = __builtin_amdgcn_mfma_f32_16x16x32_bf16(c2, wl[1][0][ks], acc1, 0, 0, 0);
  }
  // C/D layout: n = l15 (weight row), m = l4*4 + i (batch within tile)
#pragma unroll
  for (int i = 0; i < 4; ++i) {
    sm.u.gs[ksl][half * 32 + l4 * 4 + i][l15] = acc0[i];
    sm.u.gs[ksl][half * 32 + 16 + l4 * 4 + i][l15] = acc1[i];
  }
  __syncthreads();
  if (tid < 256) {                           // cell: 64 batches x 4 cols
    const int b = tid >> 2, c = tid & 3, j = blk * 4 + c;
    float g0 = 0.f, g1 = 0.f, g2 = 0.f, g3 = 0.f;
#pragma unroll
    for (int k2 = 0; k2 < 4; ++k2) {
      g0 += sm.u.gs[k2][b][c];
      g1 += sm.u.gs[k2][b][4 + c];
      g2 += sm.u.gs[k2][b][8 + c];
      g3 += sm.u.gs[k2][b][12 + c];
    }
    g0 += bl_[l * 2048 + j];
    g1 += bl_[l * 2048 + 512 + j];
    g2 += bl_[l * 2048 + 1024 + j];
    g3 += bl_[l * 2048 + 1536 + j];
    const size_t o = (size_t)l * BATCH * HID + (size_t)b * HID + j;
    float cn = sigm(g1) * cbuf[o] + sigm(g0) * tanhf(g2);
    float hn = sigm(g3) * tanhf(cn);
    cbuf[o] = cn; hbuf[o] = hn;
    unsigned short hv = f2bf(hn);
    ho_hi[b * HID + j] = hv; ho_lo[b * HID + j] = f2bf(hn - bf2f(hv));
  }
  __syncthreads();
}

// ---- logits tile: 250 blocks x 8 waves; wave w = vsub; 4 b-combos per wave ----
__device__ __forceinline__ void logits_block(int blk, int tid,
    const unsigned short* __restrict__ h1hi,
    const float4 gc0, const float4 gc1, const float4 gc2, const float4 gc3,
    float* __restrict__ red, Smem& sm) {
  const int v0 = blk * 128;
  const int lane = tid & 63, w = tid >> 6;
  const int l15 = lane & 15, l4 = lane >> 4;
  const int arow = w * 16 + l15;
  const char* abase = reinterpret_cast<const char*>(sm.embl) + arow * 1024;
  const int axor = (arow & 7) << 4;

  f32x4 acc[4];
#pragma unroll
  for (int cb = 0; cb < 4; ++cb) acc[cb] = (f32x4){0.f, 0.f, 0.f, 0.f};
#pragma unroll
  for (int ks = 0; ks < 16; ++ks) {
    bf16x8 a0 = *reinterpret_cast<const bf16x8*>(abase + ((ks * 64 + l4 * 16) ^ axor));
#pragma unroll
    for (int cb = 0; cb < 4; ++cb) {
      const int brow = cb * 16 + l15;
      bf16x8 bb = *reinterpret_cast<const bf16x8*>(h1hi + (size_t)brow * 512 + ks * 32 + l4 * 8);
      acc[cb] = __builtin_amdgcn_mfma_f32_16x16x32_bf16(a0, bb, acc[cb], 0, 0, 0);
    }
  }

  const int vb = v0 + w * 16 + l4 * 4;
#pragma unroll
  for (int cb = 0; cb < 4; ++cb) {
    const float4 g0 = (cb == 0) ? gc0 : (cb == 1) ? gc1 : (cb == 2) ? gc2 : gc3;
    float lg[4] = {acc[cb][0], acc[cb][1], acc[cb][2], acc[cb][3]};
    float gv[4] = {g0.x, g0.y, g0.z, g0.w};
    float mx = fmaxf(fmaxf(lg[0], lg[1]), fmaxf(lg[2], lg[3]));
    float ss = 0.f;
    float v1 = -INFINITY, v2 = -INFINITY; int i1 = 0x7fffffff, i2 = 0x7fffffff;
#pragma unroll
    for (int i = 0; i < 4; ++i) {
      ss += expf(lg[i] - mx);
      float val = lg[i] + gv[i];
      int idx = vb + i;
      if (better(val, idx, v1, i1)) { v2 = v1; i2 = i1; v1 = val; i1 = idx; }
      else if (better(val, idx, v2, i2)) { v2 = val; i2 = idx; }
    }
#pragma unroll
    for (int mask = 16; mask <= 32; mask <<= 1) {
      float om = __shfl_xor(mx, mask);
      float os = __shfl_xor(ss, mask);
      float u1 = __shfl_xor(v1, mask); int j1 = __shfl_xor(i1, mask);
      float u2 = __shfl_xor(v2, mask); int j2 = __shfl_xor(i2, mask);
      lse_merge(mx, ss, om, os);
      top2_merge(v1, i1, v2, i2, u1, j1, u2, j2);
    }
    if (lane < 16) {
      int slot = (w * 4 + cb) * 16 + l15;
      sm.u.c.rm[slot] = mx; sm.u.c.rs[slot] = ss;
      sm.u.c.rv1[slot] = v1; sm.u.c.ri1[slot] = i1; sm.u.c.rv2[slot] = v2; sm.u.c.ri2[slot] = i2;
    }
  }
  __syncthreads();
  if (tid < 64) {
    const int b = tid, cb = b >> 4, c = b & 15;
    int s0 = cb * 16 + c;                        // vsub = 0
    float M = sm.u.c.rm[s0], S = sm.u.c.rs[s0], V1 = sm.u.c.rv1[s0], V2 = sm.u.c.rv2[s0];
    int I1 = sm.u.c.ri1[s0], I2 = sm.u.c.ri2[s0];
#pragma unroll
    for (int vs = 1; vs < 8; ++vs) {
      int sl = (vs * 4 + cb) * 16 + c;
      lse_merge(M, S, sm.u.c.rm[sl], sm.u.c.rs[sl]);
      top2_merge(V1, I1, V2, I2, sm.u.c.rv1[sl], sm.u.c.ri1[sl], sm.u.c.rv2[sl], sm.u.c.ri2[sl]);
    }
    float* rp = red + ((size_t)blk * 64 + tid) * 8;
    rp[0] = M; rp[1] = S;
    rp[2] = V1; rp[3] = __int_as_float(I1);
    rp[4] = V2; rp[5] = __int_as_float(I2);
  }
}

// ---- final reduce + exact f32 rescore + sample (512 threads) ----
__device__ __forceinline__ void sample_block(int b, int tid, int t,
    const float* __restrict__ red, const float* __restrict__ emb,
    const float* __restrict__ h1f, const float* __restrict__ gum_t,
    unsigned short* __restrict__ xhi, unsigned short* __restrict__ xlo,
    float* __restrict__ out, Smem& sm) {
  if (tid < 256) {
    float m = -INFINITY, s = 0.f, v1 = -INFINITY, v2 = -INFINITY;
    int i1 = 0x7fffffff, i2 = 0x7fffffff;
    if (tid < NVT) {
      const float* rp = red + ((size_t)tid * 64 + b) * 8;
      m = rp[0]; s = rp[1];
      v1 = rp[2]; i1 = __float_as_int(rp[3]);
      v2 = rp[4]; i2 = __float_as_int(rp[5]);
    }
    sm.u.d.rm[tid] = m; sm.u.d.rs[tid] = s;
    sm.u.d.rv1[tid] = v1; sm.u.d.ri1[tid] = i1; sm.u.d.rv2[tid] = v2; sm.u.d.ri2[tid] = i2;
  }
  __syncthreads();
  for (int off = 128; off > 0; off >>= 1) {
    if (tid < off) {
      float M = sm.u.d.rm[tid], S = sm.u.d.rs[tid];
      lse_merge(M, S, sm.u.d.rm[tid + off], sm.u.d.rs[tid + off]);
      sm.u.d.rm[tid] = M; sm.u.d.rs[tid] = S;
      float a1 = sm.u.d.rv1[tid], a2 = sm.u.d.rv2[tid]; int c1 = sm.u.d.ri1[tid], c2 = sm.u.d.ri2[tid];
      top2_merge(a1, c1, a2, c2, sm.u.d.rv1[tid + off], sm.u.d.ri1[tid + off],
                 sm.u.d.rv2[tid + off], sm.u.d.ri2[tid + off]);
      sm.u.d.rv1[tid] = a1; sm.u.d.ri1[tid] = c1; sm.u.d.rv2[tid] = a2; sm.u.d.ri2[tid] = c2;
    }
    __syncthreads();
  }
  const int I1 = sm.u.d.ri1[0], I2 = sm.u.d.ri2[0];
  const float lse = sm.u.d.rm[0] + logf(sm.u.d.rs[0]);
  const float* e1 = emb + (size_t)I1 * EMBN;
  const float* e2 = emb + (size_t)I2 * EMBN;
  const float* hb = h1f + b * EMBN;
  {
    float hv = hb[tid];
    sm.u.d.s1[tid] = e1[tid] * hv;
    sm.u.d.s2[tid] = e2[tid] * hv;
  }
  __syncthreads();
  for (int off = 256; off > 0; off >>= 1) {
    if (tid < off) { sm.u.d.s1[tid] += sm.u.d.s1[tid + off]; sm.u.d.s2[tid] += sm.u.d.s2[tid + off]; }
    __syncthreads();
  }
  const float d1 = sm.u.d.s1[0], d2 = sm.u.d.s2[0];
  const float x1 = d1 + gum_t[(size_t)b * VOC + I1];
  const float x2 = d2 + gum_t[(size_t)b * VOC + I2];
  int tok; float dsel;
  if (x2 > x1 || (x2 == x1 && I2 < I1)) { tok = I2; dsel = d2; }
  else                                  { tok = I1; dsel = d1; }
  {
    float ev = emb[(size_t)tok * EMBN + tid];
    unsigned short hv = f2bf(ev);
    xhi[b * EMBN + tid] = hv;
    xlo[b * EMBN + tid] = f2bf(ev - bf2f(hv));
  }
  if (tid == 0) {
    out[b * TSTEPS + t] = (float)tok;
    out[BATCH * TSTEPS + b * TSTEPS + t] = dsel - lse;
  }
}

// ================= persistent decode kernel: 256 blocks x 512 threads =================
__global__ __launch_bounds__(NTHR, 2) void k_persist(
    const unsigned short* __restrict__ embbf, const float* __restrict__ emb,
    const float* __restrict__ gum, const unsigned short* __restrict__ wg,
    const float* __restrict__ b_l, float* __restrict__ hbuf, float* __restrict__ cbuf,
    unsigned short* __restrict__ xhi, unsigned short* __restrict__ xlo,
    unsigned short* __restrict__ hshi, unsigned short* __restrict__ hslo,
    float* __restrict__ red, float* __restrict__ out, unsigned* __restrict__ bar) {
  __shared__ Smem sm;
  const int blk = blockIdx.x, tid = threadIdx.x;
  const size_t HS = (size_t)BATCH * HID;   // per (parity,layer) slot
  const int lane = tid & 63, w = tid >> 6;
  const int l15 = lane & 15, l4 = lane >> 4;
  const int ksl = w & 3, half = w >> 2;    // LSTM wave roles
  const size_t WGM = (size_t)G4 * 512;

  // ---- one-time: pin this block's LSTM weight slice in registers (128 VGPR/thread) ----
  // block owns 16 weight rows: row(g,c) = g*512 + blk*4 + c ; lane l15 -> (g=l15>>2, c=l15&3)
  // wave's K slice: [ksl*128, ksl*128+128) ; wr[layer][mat][part][ks] (static idx only)
  bf16x8 wr[2][2][2][4];
  if (blk < NLSTM) {
    const int wrow = (l15 >> 2) * 512 + blk * 4 + (l15 & 3);
#pragma unroll
    for (int l = 0; l < 2; ++l)
#pragma unroll
      for (int m = 0; m < 2; ++m)
#pragma unroll
        for (int p = 0; p < 2; ++p) {
          const unsigned short* base = wg + (((size_t)l * 2 + m) * 2 + p) * WGM
                                          + (size_t)wrow * 512 + ksl * 128 + l4 * 8;
#pragma unroll
          for (int ks = 0; ks < 4; ++ks) {
            wr[l][m][p][ks] = *reinterpret_cast<const bf16x8*>(base + ks * 32);
            pin(wr[l][m][p][ks]);            // anti-remat: must stay live in VGPRs
          }
        }
  }

  // ---- one-time: stage this block's emb v-tile into LDS (persistent, XOR-swizzled) ----
  if (blk < NVT) {
    const uint4* ep = reinterpret_cast<const uint4*>(embbf + (size_t)blk * 128 * 512);
#pragma unroll
    for (int i = 0; i < 16; ++i) {
      int c = tid + i * NTHR;              // 16B chunk, 8192 total (64 per row)
      int row = c >> 6;
      int inb = (c & 63) << 4;
      uint4 v = ep[c];
      int sw = inb ^ ((row & 7) << 4);
      *reinterpret_cast<uint4*>(reinterpret_cast<char*>(sm.embl) + row * 1024 + sw) = v;
    }
  }
  __syncthreads();

  for (int t = 0; t < TSTEPS; ++t) {
    const float* gum_t = gum + (size_t)t * BATCH * VOC;
    const int p = t & 1, q = p ^ 1;

    // pre-load this thread's phase-C gumbel values -> in flight across LSTM + barrier
    float4 gc0 = make_float4(0.f, 0.f, 0.f, 0.f), gc1 = gc0, gc2 = gc0, gc3 = gc0;
    if (blk < NVT) {
      const int vb_ = blk * 128 + w * 16 + l4 * 4;
      gc0 = *reinterpret_cast<const float4*>(gum_t + (size_t)(0 * 16 + l15) * VOC + vb_);
      gc1 = *reinterpret_cast<const float4*>(gum_t + (size_t)(1 * 16 + l15) * VOC + vb_);
      gc2 = *reinterpret_cast<const float4*>(gum_t + (size_t)(2 * 16 + l15) * VOC + vb_);
      gc3 = *reinterpret_cast<const float4*>(gum_t + (size_t)(3 * 16 + l15) * VOC + vb_);
    }

    if (blk < NLSTM) {
      // phase A: layer 0 (x, h0[p] -> h0[q])
      lstm_phase(wr[0], blk, tid, half, ksl, 0, xhi, xlo,
                 hshi + ((size_t)p * 2 + 0) * HS, hslo + ((size_t)p * 2 + 0) * HS,
                 b_l, hbuf, cbuf,
                 hshi + ((size_t)q * 2 + 0) * HS, hslo + ((size_t)q * 2 + 0) * HS, sm);
      minibar(bar);
      // phase B: layer 1 (h0[q], h1[p] -> h1[q])
      lstm_phase(wr[1], blk, tid, half, ksl, 1,
                 hshi + ((size_t)q * 2 + 0) * HS, hslo + ((size_t)q * 2 + 0) * HS,
                 hshi + ((size_t)p * 2 + 1) * HS, hslo + ((size_t)p * 2 + 1) * HS,
                 b_l, hbuf, cbuf,
                 hshi + ((size_t)q * 2 + 1) * HS, hslo + ((size_t)q * 2 + 1) * HS, sm);
    }
    fullbar(bar);
    // phase C: logits (emb from LDS) + LSE + top-2 screening
    if (blk < NVT)
      logits_block(blk, tid, hshi + ((size_t)q * 2 + 1) * HS, gc0, gc1, gc2, gc3, red, sm);
    fullbar(bar);
    // phase D: final reduce + exact rescore + sample (blocks 128..191)
    if (blk >= NLSTM && blk < NLSTM + BATCH)
      sample_block(blk - NLSTM, tid, t, red, emb, hbuf + HS, gum_t, xhi, xlo, out, sm);
    fullbar(bar);
  }
}

}  // namespace

extern "C" void kernel_launch(void* const* d_in, const int* in_sizes, int n_in,
                              void* d_out, int out_size, void* d_ws, size_t ws_size,
                              hipStream_t stream) {
  const float* img  = (const float*)d_in[0];
  const float* W_fh = (const float*)d_in[1];
  const float* b_fh = (const float*)d_in[2];
  const float* Wc   = (const float*)d_in[3];
  const float* bc   = (const float*)d_in[4];
  const float* Wh   = (const float*)d_in[5];
  const float* bh   = (const float*)d_in[6];
  const float* W_ih = (const float*)d_in[7];
  const float* W_hh = (const float*)d_in[8];
  const float* b_l  = (const float*)d_in[9];
  const float* emb  = (const float*)d_in[10];
  const float* gum  = (const float*)d_in[11];
  float* out = (float*)d_out;

  float* w     = (float*)d_ws;
  float* femb  = w;                                    // 3136*512
  float* fmean = femb + (size_t)3136 * 512;            // 64*512
  float* hbuf  = fmean + 64 * 512;                     // 2*64*512 f32
  float* cbuf  = hbuf + 2 * 64 * 512;                  // 2*64*512 f32
  float* red   = cbuf + 2 * 64 * 512;                  // 250*64*8
  unsigned* bar = (unsigned*)(red + 250 * 64 * 8);     // 512 uints

  unsigned short* us = (unsigned short*)(bar + 512);
  unsigned short* embbf  = us;                                  // 32000*512
  unsigned short* imghi  = embbf + (size_t)VOC * EMBN;          // 3136*2048
  unsigned short* imglo  = imghi + (size_t)3136 * 2048;
  unsigned short* wfh_hi = imglo + (size_t)3136 * 2048;         // 512*2048 (W_fh^T)
  unsigned short* wfh_lo = wfh_hi + (size_t)512 * 2048;
  unsigned short* wg     = wfh_lo + (size_t)512 * 2048;         // [l][mat][hi/lo][2048][512]
  const size_t WGM = (size_t)G4 * 512;
  unsigned short* xhi    = wg + 8 * WGM;                        // 64*512
  unsigned short* xlo    = xhi + 64 * 512;
  unsigned short* hshi   = xlo + 64 * 512;                      // [2 parity][2 layer][64][512]
  unsigned short* hslo   = hshi + (size_t)4 * 64 * 512;

  auto wgp = [&](int l, int mat, int part_) -> unsigned short* {
    return wg + (((size_t)l * 2 + mat) * 2 + part_) * WGM;
  };

  // ---- one-time prep ----
  k_emb2bf<<<8000, 256, 0, stream>>>(emb, embbf);
  k_split<<<3136 * 2048 / 8 / 256, 256, 0, stream>>>(img, imghi, imglo);
  k_trans<<<dim3(FEATN / 32, FHN / 32), 256, 0, stream>>>(W_fh, wfh_hi, wfh_lo, FEATN, FHN);
  for (int l = 0; l < 2; ++l) {
    k_trans<<<dim3(EMBN / 32, G4 / 32), 256, 0, stream>>>(W_ih + (size_t)l * EMBN * G4, wgp(l, 0, 0), wgp(l, 0, 1), EMBN, G4);
    k_trans<<<dim3(HID / 32, G4 / 32), 256, 0, stream>>>(W_hh + (size_t)l * HID * G4, wgp(l, 1, 0), wgp(l, 1, 1), HID, G4);
  }
  k_feat_mfma<<<dim3(49, 8), 256, 0, stream>>>(imghi, imglo, wfh_hi, wfh_lo, b_fh, femb);
  k_mean<<<128, 256, 0, stream>>>(femb, fmean);
  k_h0c0<<<dim3(8, 2, 2), 256, 0, stream>>>(fmean, Wc, bc, Wh, bh, hbuf, cbuf, hshi, hslo);
  k_initx<<<128, 256, 0, stream>>>(xhi, xlo);
  k_zero<<<1, 512, 0, stream>>>(bar);

  // ---- persistent decode: emb in LDS, LSTM weights pinned in VGPRs (512 thr, 256 VGPR) ----
  k_persist<<<NBLK, NTHR, 0, stream>>>(embbf, emb, gum, wg, b_l, hbuf, cbuf,
                                       xhi, xlo, hshi, hslo, red, out, bar);
}